// Round 2
// baseline (3169.570 us; speedup 1.0000x reference)
//
#include <hip/hip_runtime.h>
#include <hip/hip_bf16.h>

#define N_NODES 100000
#define N_EDGES 400000
#define F_NODE_ 64
#define F_EDGE_ 16
#define HID_ 128
#define N_GRAPH 1024
#define N_TASK 5

// ---------------- GEMM: C[M,128] = A[M,K] @ W[K,128] + bias, K in {64,128}, all f32 ----------------
// Block 256 threads computes a 64x128 output tile; K chunked by 64 (LDS: 16KB A + 32KB W).
__global__ __launch_bounds__(256) void k_gemm(const float* __restrict__ A,
                                              const float* __restrict__ W,
                                              const float* __restrict__ bias,
                                              float* __restrict__ C, int M, int K){
  __shared__ alignas(16) float AS[64*64];    // [row][kc]
  __shared__ alignas(16) float WS[64*128];   // [kc][c]
  const int t = threadIdx.x;
  const int r0 = blockIdx.x * 64;
  const int c  = t & 127;
  const int rg = t >> 7;  // 0..1, rows rg + 2*j
  float acc[32];
  #pragma unroll
  for (int j=0;j<32;j++) acc[j] = 0.f;

  for (int kc0 = 0; kc0 < K; kc0 += 64){
    // stage A chunk: 64 rows x 16 float4
    {
      const int nv = 64*16;
      for (int i = t; i < nv; i += 256){
        int r = i >> 4, kk = (i & 15) << 2;
        float4 v = make_float4(0.f,0.f,0.f,0.f);
        if (r0 + r < M) v = *(const float4*)&A[(size_t)(r0+r)*K + kc0 + kk];
        *(float4*)&AS[r*64 + kk] = v;
      }
    }
    // stage W chunk: 64 k-rows x 32 float4
    {
      const int nv = 64*32;
      for (int i = t; i < nv; i += 256){
        int k = i >> 5, cc = (i & 31) << 2;
        *(float4*)&WS[k*128 + cc] = *(const float4*)&W[(size_t)(kc0+k)*128 + cc];
      }
    }
    __syncthreads();
    for (int k=0;k<64;k+=4){
      float w0 = WS[(k+0)*128 + c];
      float w1 = WS[(k+1)*128 + c];
      float w2 = WS[(k+2)*128 + c];
      float w3 = WS[(k+3)*128 + c];
      #pragma unroll
      for (int j=0;j<32;j++){
        const float4 a = *(const float4*)&AS[(rg + 2*j)*64 + k];
        acc[j] += a.x*w0 + a.y*w1 + a.z*w2 + a.w*w3;
      }
    }
    __syncthreads();
  }
  const float bc = bias[c];
  #pragma unroll
  for (int j=0;j<32;j++){
    int r = r0 + rg + 2*j;
    if (r < M) C[(size_t)r*128 + c] = acc[j] + bc;
  }
}

// ---------------- Edge scores: p = exp(att . leakyrelu(xl[src]+xr[dst]+ea@We)), denom scatter ----------------
#define EPW 8  // edges per wave
__global__ __launch_bounds__(256) void k_edge_score(const float* __restrict__ xl,
                                                    const float* __restrict__ xr,
                                                    const float* __restrict__ ea,
                                                    const int* __restrict__ ei,
                                                    const float* __restrict__ We,
                                                    const float* __restrict__ att,
                                                    float* __restrict__ p,
                                                    float* __restrict__ denom){
  __shared__ float WeS[16*128];
  __shared__ float attS[128];
  const int t = threadIdx.x;
  for (int i=t;i<16*128;i+=256) WeS[i] = We[i];
  if (t < 128) attS[t] = att[t];
  __syncthreads();
  const int wave = t >> 6, lane = t & 63;
  const long e0 = ((long)blockIdx.x * 4 + wave) * EPW;
  const int c0 = lane*2;
  const int h  = lane >> 4;    // head = c0/32
  const float a0 = attS[c0], a1 = attS[c0+1];
  for (int ii=0; ii<EPW; ii++){
    long e = e0 + ii;
    if (e >= N_EDGES) break;
    int src = ei[e], dst = ei[N_EDGES + e];
    float2 vl = *(const float2*)(xl + (size_t)src*HID_ + c0);
    float2 vr = *(const float2*)(xr + (size_t)dst*HID_ + c0);
    float ee0 = 0.f, ee1 = 0.f;
    const float* eap = ea + (size_t)e*F_EDGE_;
    #pragma unroll
    for (int k=0;k<F_EDGE_;k++){
      float av = eap[k];
      ee0 += av * WeS[k*128 + c0];
      ee1 += av * WeS[k*128 + c0 + 1];
    }
    float v0 = vl.x + vr.x + ee0;
    float v1 = vl.y + vr.y + ee1;
    v0 = v0 > 0.f ? v0 : 0.2f*v0;
    v1 = v1 > 0.f ? v1 : 0.2f*v1;
    float s = v0*a0 + v1*a1;
    s += __shfl_xor(s, 1);
    s += __shfl_xor(s, 2);
    s += __shfl_xor(s, 4);
    s += __shfl_xor(s, 8);
    if ((lane & 15) == 0){
      float pe = __expf(s);
      p[(size_t)e*4 + h] = pe;
      atomicAdd(&denom[(size_t)dst*4 + h], pe);
    }
  }
}

// ---------------- Aggregate: aggr[dst] += (p/denom[dst]) * xl[src] ----------------
__global__ __launch_bounds__(256) void k_edge_aggr(const float* __restrict__ xl,
                                                   const int* __restrict__ ei,
                                                   const float* __restrict__ p,
                                                   const float* __restrict__ denom,
                                                   float* __restrict__ aggr){
  const int t = threadIdx.x;
  const int wave = t >> 6, lane = t & 63;
  const long e0 = ((long)blockIdx.x * 4 + wave) * EPW;
  const int c0 = lane*2;
  const int h  = lane >> 4;
  for (int ii=0; ii<EPW; ii++){
    long e = e0 + ii;
    if (e >= N_EDGES) break;
    int src = ei[e], dst = ei[N_EDGES + e];
    float alpha = p[(size_t)e*4 + h] / (denom[(size_t)dst*4 + h] + 1e-16f);
    float2 vl = *(const float2*)(xl + (size_t)src*HID_ + c0);
    atomicAdd(&aggr[(size_t)dst*HID_ + c0],     alpha * vl.x);
    atomicAdd(&aggr[(size_t)dst*HID_ + c0 + 1], alpha * vl.y);
  }
}

// ---------------- BN stats: per-channel sum & sumsq ----------------
__global__ __launch_bounds__(256) void k_bn_stats(const float* __restrict__ aggr,
                                                  float* __restrict__ stats){
  __shared__ float redS[256], redS2[256];
  const int t = threadIdx.x;
  const int c = t & 127, half = t >> 7;
  float s = 0.f, s2 = 0.f;
  for (int r = blockIdx.x*2 + half; r < N_NODES; r += gridDim.x*2){
    float v = aggr[(size_t)r*HID_ + c];
    s += v; s2 += v*v;
  }
  redS[t] = s; redS2[t] = s2;
  __syncthreads();
  if (half == 0){
    s  += redS[t+128];
    s2 += redS2[t+128];
    atomicAdd(&stats[c], s);
    atomicAdd(&stats[128+c], s2);
  }
}

// ---------------- BN apply + ELU (+ residual), write h ----------------
__global__ __launch_bounds__(256) void k_bn_apply(const float* __restrict__ aggr,
                                                  const float* __restrict__ stats,
                                                  const float* __restrict__ gamma,
                                                  const float* __restrict__ beta,
                                                  float* __restrict__ h, int residual){
  size_t i = (size_t)blockIdx.x*256 + threadIdx.x;
  if (i >= (size_t)N_NODES*HID_) return;
  int c = i & 127;
  const float invn = 1.0f / (float)N_NODES;
  float mu  = stats[c] * invn;
  float var = stats[128+c] * invn - mu*mu;
  float sc  = rsqrtf(var + 1e-5f) * gamma[c];
  float val = (aggr[i] - mu) * sc + beta[c];
  val = val > 0.f ? val : expm1f(val);
  if (residual) val += h[i];
  h[i] = val;
}

// ---------------- Pool: segment-mean numerators + counts ----------------
__global__ __launch_bounds__(256) void k_pool(const float* __restrict__ h,
                                              const int* __restrict__ batch,
                                              float* __restrict__ emb,
                                              float* __restrict__ cnt){
  size_t i = (size_t)blockIdx.x*256 + threadIdx.x;
  if (i >= (size_t)N_NODES*HID_) return;
  int r = i >> 7, c = i & 127;
  int g = batch[r];
  atomicAdd(&emb[(size_t)g*HID_ + c], h[i]);
  if (c == 0) atomicAdd(&cnt[g], 1.0f);
}

// ---------------- Per-task heads ----------------
__global__ __launch_bounds__(128) void k_heads(const float* __restrict__ emb,
                                               const float* __restrict__ cnt,
                                               const float* __restrict__ mf,
                                               const int* __restrict__ fpi,
                                               const float* __restrict__ tw1,
                                               const float* __restrict__ tb1,
                                               const float* __restrict__ tw2,
                                               const float* __restrict__ tb2,
                                               float* __restrict__ out){
  const int g = blockIdx.x, task = blockIdx.y;
  const int j = threadIdx.x;
  __shared__ float fused[160];
  __shared__ float red[128];
  float c = cnt[g]; c = c < 1.f ? 1.f : c;
  fused[j] = emb[(size_t)g*HID_ + j] / c;
  if (j < 32){
    int bit = fpi[task*32 + j];
    fused[128 + j] = mf[(size_t)g*2048 + bit];
  }
  __syncthreads();
  const float* w1 = tw1 + (size_t)task*160*128;
  float acc = tb1[task*128 + j];
  #pragma unroll 8
  for (int i=0;i<160;i++) acc += fused[i] * w1[(size_t)i*128 + j];
  acc = acc > 0.f ? acc : 0.f;
  acc *= tw2[task*128 + j];
  red[j] = acc;
  __syncthreads();
  for (int s=64; s>0; s>>=1){
    if (j < s) red[j] += red[j+s];
    __syncthreads();
  }
  if (j == 0) out[(size_t)g*N_TASK + task] = red[0] + tb2[task];
}

extern "C" void kernel_launch(void* const* d_in, const int* in_sizes, int n_in,
                              void* d_out, int out_size, void* d_ws, size_t ws_size,
                              hipStream_t stream){
  const float* x    = (const float*)d_in[0];
  const int*   ei   = (const int*)  d_in[1];
  const float* ea   = (const float*)d_in[2];
  const int*   batch= (const int*)  d_in[3];
  const float* mf   = (const float*)d_in[4];
  const int*   fpi  = (const int*)  d_in[5];
  const float* Wl0  = (const float*)d_in[6];
  const float* bl0  = (const float*)d_in[7];
  const float* Wr0  = (const float*)d_in[8];
  const float* br0  = (const float*)d_in[9];
  const float* We0  = (const float*)d_in[10];
  const float* att0 = (const float*)d_in[11];
  // d_in[12] = bias0: cancels under BatchNorm mean-subtraction
  const float* g0   = (const float*)d_in[13];
  const float* b0   = (const float*)d_in[14];
  const float* Wl   = (const float*)d_in[15];
  const float* bl   = (const float*)d_in[16];
  const float* Wr   = (const float*)d_in[17];
  const float* br   = (const float*)d_in[18];
  const float* We   = (const float*)d_in[19];
  const float* att  = (const float*)d_in[20];
  // d_in[21] = biasc: cancels under BatchNorm
  const float* gg   = (const float*)d_in[22];
  const float* bb   = (const float*)d_in[23];
  const float* tw1  = (const float*)d_in[24];
  const float* tb1  = (const float*)d_in[25];
  const float* tw2  = (const float*)d_in[26];
  const float* tb2  = (const float*)d_in[27];
  float* out = (float*)d_out;

  char* w = (char*)d_ws;
  auto alloc = [&](size_t bytes)->char*{ char* r = w; w += (bytes + 255) & ~(size_t)255; return r; };
  float* xl    = (float*)alloc((size_t)N_NODES*HID_*4);
  float* xr    = (float*)alloc((size_t)N_NODES*HID_*4);
  float* h     = (float*)alloc((size_t)N_NODES*HID_*4);
  float* p     = (float*)alloc((size_t)N_EDGES*4*4);
  float* denom = (float*)alloc((size_t)N_NODES*4*4);
  float* aggr  = (float*)alloc((size_t)N_NODES*HID_*4);
  float* stats = (float*)alloc(256*4);
  float* emb   = (float*)alloc((size_t)N_GRAPH*HID_*4);
  float* cnt   = (float*)alloc((size_t)N_GRAPH*4);

  const int gemm_grid = (N_NODES + 63)/64;
  const int edge_grid = (N_EDGES + 4*EPW - 1)/(4*EPW);

  for (int layer = 0; layer < 4; layer++){
    const float *Wl_, *bl_, *Wr_, *br_, *We_, *att_, *g_, *b_, *Ain;
    int K;
    if (layer == 0){
      Wl_=Wl0; bl_=bl0; Wr_=Wr0; br_=br0; We_=We0; att_=att0; g_=g0; b_=b0;
      Ain = x; K = F_NODE_;
    } else {
      int i = layer - 1;
      Wl_ = Wl + (size_t)i*HID_*HID_;  bl_ = bl + (size_t)i*HID_;
      Wr_ = Wr + (size_t)i*HID_*HID_;  br_ = br + (size_t)i*HID_;
      We_ = We + (size_t)i*F_EDGE_*HID_;
      att_= att + (size_t)i*HID_;
      g_  = gg + (size_t)i*HID_;       b_  = bb + (size_t)i*HID_;
      Ain = h; K = HID_;
    }
    hipLaunchKernelGGL(k_gemm, dim3(gemm_grid), dim3(256), 0, stream, Ain, Wl_, bl_, xl, N_NODES, K);
    hipLaunchKernelGGL(k_gemm, dim3(gemm_grid), dim3(256), 0, stream, Ain, Wr_, br_, xr, N_NODES, K);
    hipMemsetAsync(denom, 0, (size_t)N_NODES*4*4, stream);
    hipMemsetAsync(aggr,  0, (size_t)N_NODES*HID_*4, stream);
    hipMemsetAsync(stats, 0, 256*4, stream);
    hipLaunchKernelGGL(k_edge_score, dim3(edge_grid), dim3(256), 0, stream, xl, xr, ea, ei, We_, att_, p, denom);
    hipLaunchKernelGGL(k_edge_aggr,  dim3(edge_grid), dim3(256), 0, stream, xl, ei, p, denom, aggr);
    hipLaunchKernelGGL(k_bn_stats,   dim3(512), dim3(256), 0, stream, aggr, stats);
    hipLaunchKernelGGL(k_bn_apply,   dim3((N_NODES*HID_ + 255)/256), dim3(256), 0, stream,
                       aggr, stats, g_, b_, h, layer > 0 ? 1 : 0);
  }
  hipMemsetAsync(emb, 0, (size_t)N_GRAPH*HID_*4, stream);
  hipMemsetAsync(cnt, 0, (size_t)N_GRAPH*4, stream);
  hipLaunchKernelGGL(k_pool,  dim3((N_NODES*HID_ + 255)/256), dim3(256), 0, stream, h, batch, emb, cnt);
  hipLaunchKernelGGL(k_heads, dim3(N_GRAPH, N_TASK), dim3(128), 0, stream, emb, cnt, mf, fpi, tw1, tb1, tw2, tb2, out);
}

// Round 3
// 2248.138 us; speedup vs baseline: 1.4099x; 1.4099x over previous
//
#include <hip/hip_runtime.h>
#include <hip/hip_bf16.h>

#define N_NODES 100000
#define N_EDGES 400000
#define F_NODE_ 64
#define F_EDGE_ 16
#define HID_ 128
#define N_GRAPH 1024
#define N_TASK 5

// ---------------- GEMM: C[M,128] = A[M,K] @ W[K,128] + bias, K in {64,128}, all f32 ----------------
__global__ __launch_bounds__(256) void k_gemm(const float* __restrict__ A,
                                              const float* __restrict__ W,
                                              const float* __restrict__ bias,
                                              float* __restrict__ C, int M, int K){
  __shared__ alignas(16) float AS[64*64];    // [row][kc]
  __shared__ alignas(16) float WS[64*128];   // [kc][c]
  const int t = threadIdx.x;
  const int r0 = blockIdx.x * 64;
  const int c  = t & 127;
  const int rg = t >> 7;  // 0..1, rows rg + 2*j
  float acc[32];
  #pragma unroll
  for (int j=0;j<32;j++) acc[j] = 0.f;

  for (int kc0 = 0; kc0 < K; kc0 += 64){
    {
      const int nv = 64*16;
      for (int i = t; i < nv; i += 256){
        int r = i >> 4, kk = (i & 15) << 2;
        float4 v = make_float4(0.f,0.f,0.f,0.f);
        if (r0 + r < M) v = *(const float4*)&A[(size_t)(r0+r)*K + kc0 + kk];
        *(float4*)&AS[r*64 + kk] = v;
      }
    }
    {
      const int nv = 64*32;
      for (int i = t; i < nv; i += 256){
        int k = i >> 5, cc = (i & 31) << 2;
        *(float4*)&WS[k*128 + cc] = *(const float4*)&W[(size_t)(kc0+k)*128 + cc];
      }
    }
    __syncthreads();
    for (int k=0;k<64;k+=4){
      float w0 = WS[(k+0)*128 + c];
      float w1 = WS[(k+1)*128 + c];
      float w2 = WS[(k+2)*128 + c];
      float w3 = WS[(k+3)*128 + c];
      #pragma unroll
      for (int j=0;j<32;j++){
        const float4 a = *(const float4*)&AS[(rg + 2*j)*64 + k];
        acc[j] += a.x*w0 + a.y*w1 + a.z*w2 + a.w*w3;
      }
    }
    __syncthreads();
  }
  const float bc = bias[c];
  #pragma unroll
  for (int j=0;j<32;j++){
    int r = r0 + rg + 2*j;
    if (r < M) C[(size_t)r*128 + c] = acc[j] + bc;
  }
}

// ---------------- CSR build (once; topology shared by all 4 layers) ----------------
__global__ __launch_bounds__(256) void k_hist(const int* __restrict__ ei, int* __restrict__ counts){
  int e = blockIdx.x*256 + threadIdx.x;
  if (e < N_EDGES) atomicAdd(&counts[ei[N_EDGES + e]], 1);
}

// single-block inclusive scan over counts -> offsets[1..N], cursor[i]=exclusive
__global__ __launch_bounds__(1024) void k_scan(const int* __restrict__ counts,
                                               int* __restrict__ offsets,
                                               int* __restrict__ cursor){
  __shared__ int sbuf[1024];
  const int t = threadIdx.x;
  int base = 0;
  for (int c0 = 0; c0 < N_NODES; c0 += 1024){
    int i = c0 + t;
    int v = (i < N_NODES) ? counts[i] : 0;
    sbuf[t] = v;
    __syncthreads();
    for (int off = 1; off < 1024; off <<= 1){
      int x = (t >= off) ? sbuf[t - off] : 0;
      __syncthreads();
      sbuf[t] += x;
      __syncthreads();
    }
    int incl = sbuf[t];
    if (i < N_NODES){
      offsets[i + 1] = base + incl;
      cursor[i]      = base + incl - v;
    }
    __syncthreads();
    base += sbuf[1023];
    __syncthreads();
  }
  if (t == 0) offsets[0] = 0;
}

__global__ __launch_bounds__(256) void k_scatter(const int* __restrict__ ei,
                                                 int* __restrict__ cursor,
                                                 int* __restrict__ ssrc,
                                                 int* __restrict__ seid){
  int e = blockIdx.x*256 + threadIdx.x;
  if (e >= N_EDGES) return;
  int dst = ei[N_EDGES + e];
  int pos = atomicAdd(&cursor[dst], 1);
  ssrc[pos] = ei[e];
  seid[pos] = e;
}

// ---------------- Fused GAT: per-dst-node softmax + aggregation, no atomics ----------------
// one wave per dst node; lane covers 2 channels; head = c0/32 (16 lanes per head)
__global__ __launch_bounds__(256) void k_gat(const float* __restrict__ xl,
                                             const float* __restrict__ xr,
                                             const float* __restrict__ ea,
                                             const float* __restrict__ We,
                                             const float* __restrict__ att,
                                             const int* __restrict__ offsets,
                                             const int* __restrict__ ssrc,
                                             const int* __restrict__ seid,
                                             float* __restrict__ aggr){
  __shared__ float WeS[16*128];
  __shared__ float attS[128];
  const int t = threadIdx.x;
  for (int i=t;i<16*128;i+=256) WeS[i] = We[i];
  if (t < 128) attS[t] = att[t];
  __syncthreads();
  const int wave = t >> 6, lane = t & 63;
  const int node = blockIdx.x*4 + wave;
  if (node >= N_NODES) return;
  const int c0 = lane*2;
  const float a0 = attS[c0], a1 = attS[c0+1];
  const float2 xrv = *(const float2*)(xr + (size_t)node*HID_ + c0);
  float acc0 = 0.f, acc1 = 0.f, den = 0.f;
  const int beg = offsets[node], end = offsets[node+1];
  for (int i = beg; i < end; i++){
    int src = ssrc[i], e = seid[i];
    float2 vl = *(const float2*)(xl + (size_t)src*HID_ + c0);
    float ee0 = 0.f, ee1 = 0.f;
    const float* eap = ea + (size_t)e*F_EDGE_;
    #pragma unroll
    for (int k=0;k<F_EDGE_;k++){
      float av = eap[k];
      ee0 += av * WeS[k*128 + c0];
      ee1 += av * WeS[k*128 + c0 + 1];
    }
    float v0 = vl.x + xrv.x + ee0;
    float v1 = vl.y + xrv.y + ee1;
    v0 = v0 > 0.f ? v0 : 0.2f*v0;
    v1 = v1 > 0.f ? v1 : 0.2f*v1;
    float s = v0*a0 + v1*a1;
    s += __shfl_xor(s, 1);
    s += __shfl_xor(s, 2);
    s += __shfl_xor(s, 4);
    s += __shfl_xor(s, 8);           // all 16 lanes of the head now hold the score
    float pe = __expf(s);
    acc0 += pe * vl.x;
    acc1 += pe * vl.y;
    den  += pe;
  }
  float inv = 1.0f / (den + 1e-16f);
  float2 o = make_float2(acc0 * inv, acc1 * inv);
  *(float2*)(aggr + (size_t)node*HID_ + c0) = o;
}

// ---------------- BN stats: per-channel sum & sumsq ----------------
__global__ __launch_bounds__(256) void k_bn_stats(const float* __restrict__ aggr,
                                                  float* __restrict__ stats){
  __shared__ float redS[256], redS2[256];
  const int t = threadIdx.x;
  const int c = t & 127, half = t >> 7;
  float s = 0.f, s2 = 0.f;
  for (int r = blockIdx.x*2 + half; r < N_NODES; r += gridDim.x*2){
    float v = aggr[(size_t)r*HID_ + c];
    s += v; s2 += v*v;
  }
  redS[t] = s; redS2[t] = s2;
  __syncthreads();
  if (half == 0){
    s  += redS[t+128];
    s2 += redS2[t+128];
    atomicAdd(&stats[c], s);
    atomicAdd(&stats[128+c], s2);
  }
}

// ---------------- BN apply + ELU (+ residual), write h ----------------
__global__ __launch_bounds__(256) void k_bn_apply(const float* __restrict__ aggr,
                                                  const float* __restrict__ stats,
                                                  const float* __restrict__ gamma,
                                                  const float* __restrict__ beta,
                                                  float* __restrict__ h, int residual){
  size_t i = (size_t)blockIdx.x*256 + threadIdx.x;
  if (i >= (size_t)N_NODES*HID_) return;
  int c = i & 127;
  const float invn = 1.0f / (float)N_NODES;
  float mu  = stats[c] * invn;
  float var = stats[128+c] * invn - mu*mu;
  float sc  = rsqrtf(var + 1e-5f) * gamma[c];
  float val = (aggr[i] - mu) * sc + beta[c];
  val = val > 0.f ? val : expm1f(val);
  if (residual) val += h[i];
  h[i] = val;
}

// ---------------- Pool: segment-mean numerators + counts ----------------
__global__ __launch_bounds__(256) void k_pool(const float* __restrict__ h,
                                              const int* __restrict__ batch,
                                              float* __restrict__ emb,
                                              float* __restrict__ cnt){
  size_t i = (size_t)blockIdx.x*256 + threadIdx.x;
  if (i >= (size_t)N_NODES*HID_) return;
  int r = i >> 7, c = i & 127;
  int g = batch[r];
  atomicAdd(&emb[(size_t)g*HID_ + c], h[i]);
  if (c == 0) atomicAdd(&cnt[g], 1.0f);
}

// ---------------- Per-task heads ----------------
__global__ __launch_bounds__(128) void k_heads(const float* __restrict__ emb,
                                               const float* __restrict__ cnt,
                                               const float* __restrict__ mf,
                                               const int* __restrict__ fpi,
                                               const float* __restrict__ tw1,
                                               const float* __restrict__ tb1,
                                               const float* __restrict__ tw2,
                                               const float* __restrict__ tb2,
                                               float* __restrict__ out){
  const int g = blockIdx.x, task = blockIdx.y;
  const int j = threadIdx.x;
  __shared__ float fused[160];
  __shared__ float red[128];
  float c = cnt[g]; c = c < 1.f ? 1.f : c;
  fused[j] = emb[(size_t)g*HID_ + j] / c;
  if (j < 32){
    int bit = fpi[task*32 + j];
    fused[128 + j] = mf[(size_t)g*2048 + bit];
  }
  __syncthreads();
  const float* w1 = tw1 + (size_t)task*160*128;
  float acc = tb1[task*128 + j];
  #pragma unroll 8
  for (int i=0;i<160;i++) acc += fused[i] * w1[(size_t)i*128 + j];
  acc = acc > 0.f ? acc : 0.f;
  acc *= tw2[task*128 + j];
  red[j] = acc;
  __syncthreads();
  for (int s=64; s>0; s>>=1){
    if (j < s) red[j] += red[j+s];
    __syncthreads();
  }
  if (j == 0) out[(size_t)g*N_TASK + task] = red[0] + tb2[task];
}

extern "C" void kernel_launch(void* const* d_in, const int* in_sizes, int n_in,
                              void* d_out, int out_size, void* d_ws, size_t ws_size,
                              hipStream_t stream){
  const float* x    = (const float*)d_in[0];
  const int*   ei   = (const int*)  d_in[1];
  const float* ea   = (const float*)d_in[2];
  const int*   batch= (const int*)  d_in[3];
  const float* mf   = (const float*)d_in[4];
  const int*   fpi  = (const int*)  d_in[5];
  const float* Wl0  = (const float*)d_in[6];
  const float* bl0  = (const float*)d_in[7];
  const float* Wr0  = (const float*)d_in[8];
  const float* br0  = (const float*)d_in[9];
  const float* We0  = (const float*)d_in[10];
  const float* att0 = (const float*)d_in[11];
  // d_in[12] = bias0: cancels under BatchNorm mean-subtraction
  const float* g0   = (const float*)d_in[13];
  const float* b0   = (const float*)d_in[14];
  const float* Wl   = (const float*)d_in[15];
  const float* bl   = (const float*)d_in[16];
  const float* Wr   = (const float*)d_in[17];
  const float* br   = (const float*)d_in[18];
  const float* We   = (const float*)d_in[19];
  const float* att  = (const float*)d_in[20];
  // d_in[21] = biasc: cancels under BatchNorm
  const float* gg   = (const float*)d_in[22];
  const float* bb   = (const float*)d_in[23];
  const float* tw1  = (const float*)d_in[24];
  const float* tb1  = (const float*)d_in[25];
  const float* tw2  = (const float*)d_in[26];
  const float* tb2  = (const float*)d_in[27];
  float* out = (float*)d_out;

  char* w = (char*)d_ws;
  auto alloc = [&](size_t bytes)->char*{ char* r = w; w += (bytes + 255) & ~(size_t)255; return r; };
  float* xl     = (float*)alloc((size_t)N_NODES*HID_*4);
  float* xr     = (float*)alloc((size_t)N_NODES*HID_*4);
  float* h      = (float*)alloc((size_t)N_NODES*HID_*4);
  float* aggr   = (float*)alloc((size_t)N_NODES*HID_*4);
  float* stats  = (float*)alloc(256*4);
  float* emb    = (float*)alloc((size_t)N_GRAPH*HID_*4);
  float* cnt    = (float*)alloc((size_t)N_GRAPH*4);
  int*   counts = (int*)  alloc((size_t)N_NODES*4);
  int*   offsets= (int*)  alloc((size_t)(N_NODES+1)*4);
  int*   cursor = (int*)  alloc((size_t)N_NODES*4);
  int*   ssrc   = (int*)  alloc((size_t)N_EDGES*4);
  int*   seid   = (int*)  alloc((size_t)N_EDGES*4);

  const int gemm_grid = (N_NODES + 63)/64;
  const int eg256 = (N_EDGES + 255)/256;

  // CSR build (topology constant across layers)
  hipMemsetAsync(counts, 0, (size_t)N_NODES*4, stream);
  hipLaunchKernelGGL(k_hist,    dim3(eg256), dim3(256),  0, stream, ei, counts);
  hipLaunchKernelGGL(k_scan,    dim3(1),     dim3(1024), 0, stream, counts, offsets, cursor);
  hipLaunchKernelGGL(k_scatter, dim3(eg256), dim3(256),  0, stream, ei, cursor, ssrc, seid);

  for (int layer = 0; layer < 4; layer++){
    const float *Wl_, *bl_, *Wr_, *br_, *We_, *att_, *g_, *b_, *Ain;
    int K;
    if (layer == 0){
      Wl_=Wl0; bl_=bl0; Wr_=Wr0; br_=br0; We_=We0; att_=att0; g_=g0; b_=b0;
      Ain = x; K = F_NODE_;
    } else {
      int i = layer - 1;
      Wl_ = Wl + (size_t)i*HID_*HID_;  bl_ = bl + (size_t)i*HID_;
      Wr_ = Wr + (size_t)i*HID_*HID_;  br_ = br + (size_t)i*HID_;
      We_ = We + (size_t)i*F_EDGE_*HID_;
      att_= att + (size_t)i*HID_;
      g_  = gg + (size_t)i*HID_;       b_  = bb + (size_t)i*HID_;
      Ain = h; K = HID_;
    }
    hipLaunchKernelGGL(k_gemm, dim3(gemm_grid), dim3(256), 0, stream, Ain, Wl_, bl_, xl, N_NODES, K);
    hipLaunchKernelGGL(k_gemm, dim3(gemm_grid), dim3(256), 0, stream, Ain, Wr_, br_, xr, N_NODES, K);
    hipMemsetAsync(stats, 0, 256*4, stream);
    hipLaunchKernelGGL(k_gat, dim3((N_NODES + 3)/4), dim3(256), 0, stream,
                       xl, xr, ea, We_, att_, offsets, ssrc, seid, aggr);
    hipLaunchKernelGGL(k_bn_stats, dim3(512), dim3(256), 0, stream, aggr, stats);
    hipLaunchKernelGGL(k_bn_apply, dim3((N_NODES*HID_ + 255)/256), dim3(256), 0, stream,
                       aggr, stats, g_, b_, h, layer > 0 ? 1 : 0);
  }
  hipMemsetAsync(emb, 0, (size_t)N_GRAPH*HID_*4, stream);
  hipMemsetAsync(cnt, 0, (size_t)N_GRAPH*4, stream);
  hipLaunchKernelGGL(k_pool,  dim3((N_NODES*HID_ + 255)/256), dim3(256), 0, stream, h, batch, emb, cnt);
  hipLaunchKernelGGL(k_heads, dim3(N_GRAPH, N_TASK), dim3(128), 0, stream, emb, cnt, mf, fpi, tw1, tb1, tw2, tb2, out);
}

// Round 4
// 1690.273 us; speedup vs baseline: 1.8752x; 1.3300x over previous
//
#include <hip/hip_runtime.h>
#include <hip/hip_bf16.h>

#define N_NODES 100000
#define N_EDGES 400000
#define F_NODE_ 64
#define F_EDGE_ 16
#define HID_ 128
#define N_GRAPH 1024
#define N_TASK 5

// ---------------- GEMM: C[M,128] = A[M,K] @ W[K,128] + bias, K in {64,128}, f32 ----------------
// 128x128 block tile, BK=32, 256 threads, 8x8 register tile per thread.
#define BMT 128
#define BKT 32
#define TSTR 132   // LDS row stride (floats): 16B-aligned, breaks pow2 banks
__global__ __launch_bounds__(256) void k_gemm(const float* __restrict__ A,
                                              const float* __restrict__ W,
                                              const float* __restrict__ bias,
                                              float* __restrict__ C, int M, int K){
  __shared__ alignas(16) float AS[BKT*TSTR];  // [k][m]
  __shared__ alignas(16) float WS[BKT*TSTR];  // [k][n]
  const int t = threadIdx.x;
  const int r0 = blockIdx.x * BMT;
  const int tx = t & 15, ty = t >> 4;   // col group tx*8, row group ty*8
  float acc[8][8];
  #pragma unroll
  for (int i=0;i<8;i++)
    #pragma unroll
    for (int j=0;j<8;j++) acc[i][j] = 0.f;

  for (int kc0 = 0; kc0 < K; kc0 += BKT){
    // stage A transposed: AS[k][m] = A[r0+m][kc0+k]; 1024 float4 loads
    for (int i = t; i < 1024; i += 256){
      int m = i >> 3, kk = (i & 7) << 2;
      float4 v = make_float4(0.f,0.f,0.f,0.f);
      if (r0 + m < M) v = *(const float4*)&A[(size_t)(r0+m)*K + kc0 + kk];
      AS[(kk+0)*TSTR + m] = v.x;
      AS[(kk+1)*TSTR + m] = v.y;
      AS[(kk+2)*TSTR + m] = v.z;
      AS[(kk+3)*TSTR + m] = v.w;
    }
    // stage W: WS[k][n] = W[kc0+k][n]; 1024 float4 loads
    for (int i = t; i < 1024; i += 256){
      int k = i >> 5, nn = (i & 31) << 2;
      *(float4*)&WS[k*TSTR + nn] = *(const float4*)&W[(size_t)(kc0+k)*128 + nn];
    }
    __syncthreads();
    #pragma unroll 4
    for (int k = 0; k < BKT; k++){
      const float4 a0 = *(const float4*)&AS[k*TSTR + ty*8];
      const float4 a1 = *(const float4*)&AS[k*TSTR + ty*8 + 4];
      const float4 w0 = *(const float4*)&WS[k*TSTR + tx*8];
      const float4 w1 = *(const float4*)&WS[k*TSTR + tx*8 + 4];
      const float av[8] = {a0.x,a0.y,a0.z,a0.w,a1.x,a1.y,a1.z,a1.w};
      const float wv[8] = {w0.x,w0.y,w0.z,w0.w,w1.x,w1.y,w1.z,w1.w};
      #pragma unroll
      for (int i=0;i<8;i++)
        #pragma unroll
        for (int j=0;j<8;j++) acc[i][j] += av[i] * wv[j];
    }
    __syncthreads();
  }
  const float4 b0 = *(const float4*)&bias[tx*8];
  const float4 b1 = *(const float4*)&bias[tx*8+4];
  #pragma unroll
  for (int i=0;i<8;i++){
    int r = r0 + ty*8 + i;
    if (r < M){
      float4 o0 = make_float4(acc[i][0]+b0.x, acc[i][1]+b0.y, acc[i][2]+b0.z, acc[i][3]+b0.w);
      float4 o1 = make_float4(acc[i][4]+b1.x, acc[i][5]+b1.y, acc[i][6]+b1.z, acc[i][7]+b1.w);
      *(float4*)&C[(size_t)r*128 + tx*8]     = o0;
      *(float4*)&C[(size_t)r*128 + tx*8 + 4] = o1;
    }
  }
}

// ---------------- CSR build (once; topology shared by all 4 layers) ----------------
__global__ __launch_bounds__(256) void k_hist(const int* __restrict__ ei, int* __restrict__ counts){
  int e = blockIdx.x*256 + threadIdx.x;
  if (e < N_EDGES) atomicAdd(&counts[ei[N_EDGES + e]], 1);
}

// two-level scan: per-block inclusive scan + block sums
__global__ __launch_bounds__(512) void k_scan1(const int* __restrict__ counts,
                                               int* __restrict__ incl,
                                               int* __restrict__ bsum){
  __shared__ int s[512];
  const int t = threadIdx.x;
  int i = blockIdx.x*512 + t;
  int v = (i < N_NODES) ? counts[i] : 0;
  s[t] = v;
  __syncthreads();
  for (int off = 1; off < 512; off <<= 1){
    int x = (t >= off) ? s[t - off] : 0;
    __syncthreads();
    s[t] += x;
    __syncthreads();
  }
  if (i < N_NODES) incl[i] = s[t];
  if (t == 511) bsum[blockIdx.x] = s[511];
}

// exclusive scan of block sums (nb <= 256)
__global__ __launch_bounds__(256) void k_scan2(int* __restrict__ bsum, int nb){
  __shared__ int s[256];
  const int t = threadIdx.x;
  int v = (t < nb) ? bsum[t] : 0;
  s[t] = v;
  __syncthreads();
  for (int off = 1; off < 256; off <<= 1){
    int x = (t >= off) ? s[t - off] : 0;
    __syncthreads();
    s[t] += x;
    __syncthreads();
  }
  if (t < nb) bsum[t] = s[t] - v;   // exclusive
}

__global__ __launch_bounds__(512) void k_scan3(const int* __restrict__ counts,
                                               const int* __restrict__ incl,
                                               const int* __restrict__ bsum,
                                               int* __restrict__ offsets,
                                               int* __restrict__ cursor){
  int i = blockIdx.x*512 + threadIdx.x;
  if (i >= N_NODES) return;
  int o = bsum[blockIdx.x] + incl[i];
  offsets[i + 1] = o;
  cursor[i]      = o - counts[i];
  if (i == 0) offsets[0] = 0;
}

__global__ __launch_bounds__(256) void k_scatter(const int* __restrict__ ei,
                                                 int* __restrict__ cursor,
                                                 int* __restrict__ ssrc,
                                                 int* __restrict__ seid){
  int e = blockIdx.x*256 + threadIdx.x;
  if (e >= N_EDGES) return;
  int dst = ei[N_EDGES + e];
  int pos = atomicAdd(&cursor[dst], 1);
  ssrc[pos] = ei[e];
  seid[pos] = e;
}

// ---------------- Fused GAT: per-dst-node softmax + aggregation, no atomics ----------------
__global__ __launch_bounds__(256) void k_gat(const float* __restrict__ xl,
                                             const float* __restrict__ xr,
                                             const float* __restrict__ ea,
                                             const float* __restrict__ We,
                                             const float* __restrict__ att,
                                             const int* __restrict__ offsets,
                                             const int* __restrict__ ssrc,
                                             const int* __restrict__ seid,
                                             float* __restrict__ aggr){
  __shared__ float WeS[16*128];
  __shared__ float attS[128];
  const int t = threadIdx.x;
  for (int i=t;i<16*128;i+=256) WeS[i] = We[i];
  if (t < 128) attS[t] = att[t];
  __syncthreads();
  const int wave = t >> 6, lane = t & 63;
  const int node = blockIdx.x*4 + wave;
  if (node >= N_NODES) return;
  const int c0 = lane*2;
  const float a0 = attS[c0], a1 = attS[c0+1];
  const float2 xrv = *(const float2*)(xr + (size_t)node*HID_ + c0);
  float acc0 = 0.f, acc1 = 0.f, den = 0.f;
  const int beg = offsets[node], end = offsets[node+1];
  for (int i = beg; i < end; i++){
    int src = ssrc[i], e = seid[i];
    float2 vl = *(const float2*)(xl + (size_t)src*HID_ + c0);
    float ee0 = 0.f, ee1 = 0.f;
    const float* eap = ea + (size_t)e*F_EDGE_;
    #pragma unroll
    for (int k=0;k<F_EDGE_;k++){
      float av = eap[k];
      ee0 += av * WeS[k*128 + c0];
      ee1 += av * WeS[k*128 + c0 + 1];
    }
    float v0 = vl.x + xrv.x + ee0;
    float v1 = vl.y + xrv.y + ee1;
    v0 = v0 > 0.f ? v0 : 0.2f*v0;
    v1 = v1 > 0.f ? v1 : 0.2f*v1;
    float s = v0*a0 + v1*a1;
    s += __shfl_xor(s, 1);
    s += __shfl_xor(s, 2);
    s += __shfl_xor(s, 4);
    s += __shfl_xor(s, 8);
    float pe = __expf(s);
    acc0 += pe * vl.x;
    acc1 += pe * vl.y;
    den  += pe;
  }
  float inv = 1.0f / (den + 1e-16f);
  *(float2*)(aggr + (size_t)node*HID_ + c0) = make_float2(acc0*inv, acc1*inv);
}

// ---------------- BN stats ----------------
__global__ __launch_bounds__(256) void k_bn_stats(const float* __restrict__ aggr,
                                                  float* __restrict__ stats){
  __shared__ float redS[256], redS2[256];
  const int t = threadIdx.x;
  const int c = t & 127, half = t >> 7;
  float s = 0.f, s2 = 0.f;
  for (int r = blockIdx.x*2 + half; r < N_NODES; r += gridDim.x*2){
    float v = aggr[(size_t)r*HID_ + c];
    s += v; s2 += v*v;
  }
  redS[t] = s; redS2[t] = s2;
  __syncthreads();
  if (half == 0){
    s  += redS[t+128];
    s2 += redS2[t+128];
    atomicAdd(&stats[c], s);
    atomicAdd(&stats[128+c], s2);
  }
}

// ---------------- BN apply + ELU (+ residual) ----------------
__global__ __launch_bounds__(256) void k_bn_apply(const float* __restrict__ aggr,
                                                  const float* __restrict__ stats,
                                                  const float* __restrict__ gamma,
                                                  const float* __restrict__ beta,
                                                  float* __restrict__ h, int residual){
  size_t i = (size_t)blockIdx.x*256 + threadIdx.x;
  if (i >= (size_t)N_NODES*HID_) return;
  int c = i & 127;
  const float invn = 1.0f / (float)N_NODES;
  float mu  = stats[c] * invn;
  float var = stats[128+c] * invn - mu*mu;
  float sc  = rsqrtf(var + 1e-5f) * gamma[c];
  float val = (aggr[i] - mu) * sc + beta[c];
  val = val > 0.f ? val : expm1f(val);
  if (residual) val += h[i];
  h[i] = val;
}

// ---------------- Pool ----------------
__global__ __launch_bounds__(256) void k_pool(const float* __restrict__ h,
                                              const int* __restrict__ batch,
                                              float* __restrict__ emb,
                                              float* __restrict__ cnt){
  size_t i = (size_t)blockIdx.x*256 + threadIdx.x;
  if (i >= (size_t)N_NODES*HID_) return;
  int r = i >> 7, c = i & 127;
  int g = batch[r];
  atomicAdd(&emb[(size_t)g*HID_ + c], h[i]);
  if (c == 0) atomicAdd(&cnt[g], 1.0f);
}

// ---------------- Per-task heads ----------------
__global__ __launch_bounds__(128) void k_heads(const float* __restrict__ emb,
                                               const float* __restrict__ cnt,
                                               const float* __restrict__ mf,
                                               const int* __restrict__ fpi,
                                               const float* __restrict__ tw1,
                                               const float* __restrict__ tb1,
                                               const float* __restrict__ tw2,
                                               const float* __restrict__ tb2,
                                               float* __restrict__ out){
  const int g = blockIdx.x, task = blockIdx.y;
  const int j = threadIdx.x;
  __shared__ float fused[160];
  __shared__ float red[128];
  float c = cnt[g]; c = c < 1.f ? 1.f : c;
  fused[j] = emb[(size_t)g*HID_ + j] / c;
  if (j < 32){
    int bit = fpi[task*32 + j];
    fused[128 + j] = mf[(size_t)g*2048 + bit];
  }
  __syncthreads();
  const float* w1 = tw1 + (size_t)task*160*128;
  float acc = tb1[task*128 + j];
  #pragma unroll 8
  for (int i=0;i<160;i++) acc += fused[i] * w1[(size_t)i*128 + j];
  acc = acc > 0.f ? acc : 0.f;
  acc *= tw2[task*128 + j];
  red[j] = acc;
  __syncthreads();
  for (int s=64; s>0; s>>=1){
    if (j < s) red[j] += red[j+s];
    __syncthreads();
  }
  if (j == 0) out[(size_t)g*N_TASK + task] = red[0] + tb2[task];
}

extern "C" void kernel_launch(void* const* d_in, const int* in_sizes, int n_in,
                              void* d_out, int out_size, void* d_ws, size_t ws_size,
                              hipStream_t stream){
  const float* x    = (const float*)d_in[0];
  const int*   ei   = (const int*)  d_in[1];
  const float* ea   = (const float*)d_in[2];
  const int*   batch= (const int*)  d_in[3];
  const float* mf   = (const float*)d_in[4];
  const int*   fpi  = (const int*)  d_in[5];
  const float* Wl0  = (const float*)d_in[6];
  const float* bl0  = (const float*)d_in[7];
  const float* Wr0  = (const float*)d_in[8];
  const float* br0  = (const float*)d_in[9];
  const float* We0  = (const float*)d_in[10];
  const float* att0 = (const float*)d_in[11];
  const float* g0   = (const float*)d_in[13];
  const float* b0   = (const float*)d_in[14];
  const float* Wl   = (const float*)d_in[15];
  const float* bl   = (const float*)d_in[16];
  const float* Wr   = (const float*)d_in[17];
  const float* br   = (const float*)d_in[18];
  const float* We   = (const float*)d_in[19];
  const float* att  = (const float*)d_in[20];
  const float* gg   = (const float*)d_in[22];
  const float* bb   = (const float*)d_in[23];
  const float* tw1  = (const float*)d_in[24];
  const float* tb1  = (const float*)d_in[25];
  const float* tw2  = (const float*)d_in[26];
  const float* tb2  = (const float*)d_in[27];
  float* out = (float*)d_out;

  char* w = (char*)d_ws;
  auto alloc = [&](size_t bytes)->char*{ char* r = w; w += (bytes + 255) & ~(size_t)255; return r; };
  float* xl     = (float*)alloc((size_t)N_NODES*HID_*4);
  float* xr     = (float*)alloc((size_t)N_NODES*HID_*4);
  float* h      = (float*)alloc((size_t)N_NODES*HID_*4);
  float* aggr   = (float*)alloc((size_t)N_NODES*HID_*4);
  float* stats  = (float*)alloc(256*4);
  float* emb    = (float*)alloc((size_t)N_GRAPH*HID_*4);
  float* cnt    = (float*)alloc((size_t)N_GRAPH*4);
  int*   counts = (int*)  alloc((size_t)N_NODES*4);
  int*   offsets= (int*)  alloc((size_t)(N_NODES+1)*4);
  int*   cursor = (int*)  alloc((size_t)N_NODES*4);
  int*   incl   = (int*)  alloc((size_t)N_NODES*4);
  int*   bsum   = (int*)  alloc(256*4);
  int*   ssrc   = (int*)  alloc((size_t)N_EDGES*4);
  int*   seid   = (int*)  alloc((size_t)N_EDGES*4);

  const int gemm_grid = (N_NODES + BMT - 1)/BMT;
  const int eg256 = (N_EDGES + 255)/256;
  const int nscan = (N_NODES + 511)/512;

  // CSR build (topology constant across layers)
  hipMemsetAsync(counts, 0, (size_t)N_NODES*4, stream);
  hipLaunchKernelGGL(k_hist,    dim3(eg256), dim3(256), 0, stream, ei, counts);
  hipLaunchKernelGGL(k_scan1,   dim3(nscan), dim3(512), 0, stream, counts, incl, bsum);
  hipLaunchKernelGGL(k_scan2,   dim3(1),     dim3(256), 0, stream, bsum, nscan);
  hipLaunchKernelGGL(k_scan3,   dim3(nscan), dim3(512), 0, stream, counts, incl, bsum, offsets, cursor);
  hipLaunchKernelGGL(k_scatter, dim3(eg256), dim3(256), 0, stream, ei, cursor, ssrc, seid);

  for (int layer = 0; layer < 4; layer++){
    const float *Wl_, *bl_, *Wr_, *br_, *We_, *att_, *g_, *b_, *Ain;
    int K;
    if (layer == 0){
      Wl_=Wl0; bl_=bl0; Wr_=Wr0; br_=br0; We_=We0; att_=att0; g_=g0; b_=b0;
      Ain = x; K = F_NODE_;
    } else {
      int i = layer - 1;
      Wl_ = Wl + (size_t)i*HID_*HID_;  bl_ = bl + (size_t)i*HID_;
      Wr_ = Wr + (size_t)i*HID_*HID_;  br_ = br + (size_t)i*HID_;
      We_ = We + (size_t)i*F_EDGE_*HID_;
      att_= att + (size_t)i*HID_;
      g_  = gg + (size_t)i*HID_;       b_  = bb + (size_t)i*HID_;
      Ain = h; K = HID_;
    }
    hipLaunchKernelGGL(k_gemm, dim3(gemm_grid), dim3(256), 0, stream, Ain, Wl_, bl_, xl, N_NODES, K);
    hipLaunchKernelGGL(k_gemm, dim3(gemm_grid), dim3(256), 0, stream, Ain, Wr_, br_, xr, N_NODES, K);
    hipMemsetAsync(stats, 0, 256*4, stream);
    hipLaunchKernelGGL(k_gat, dim3((N_NODES + 3)/4), dim3(256), 0, stream,
                       xl, xr, ea, We_, att_, offsets, ssrc, seid, aggr);
    hipLaunchKernelGGL(k_bn_stats, dim3(512), dim3(256), 0, stream, aggr, stats);
    hipLaunchKernelGGL(k_bn_apply, dim3((N_NODES*HID_ + 255)/256), dim3(256), 0, stream,
                       aggr, stats, g_, b_, h, layer > 0 ? 1 : 0);
  }
  hipMemsetAsync(emb, 0, (size_t)N_GRAPH*HID_*4, stream);
  hipMemsetAsync(cnt, 0, (size_t)N_GRAPH*4, stream);
  hipLaunchKernelGGL(k_pool,  dim3((N_NODES*HID_ + 255)/256), dim3(256), 0, stream, h, batch, emb, cnt);
  hipLaunchKernelGGL(k_heads, dim3(N_GRAPH, N_TASK), dim3(128), 0, stream, emb, cnt, mf, fpi, tw1, tb1, tw2, tb2, out);
}

// Round 5
// 1508.365 us; speedup vs baseline: 2.1013x; 1.1206x over previous
//
#include <hip/hip_runtime.h>
#include <hip/hip_bf16.h>

#define N_NODES 100000
#define N_EDGES 400000
#define F_NODE_ 64
#define F_EDGE_ 16
#define HID_ 128
#define N_GRAPH 1024
#define N_TASK 5

// ---------------- GEMM: C[M,128] = A[M,K] @ W[K,128] + bias, K in {64,128}, f32 ----------------
#define BMT 128
#define BKT 32
#define TSTR 132
__global__ __launch_bounds__(256) void k_gemm(const float* __restrict__ A,
                                              const float* __restrict__ W,
                                              const float* __restrict__ bias,
                                              float* __restrict__ C, int M, int K){
  __shared__ alignas(16) float AS[BKT*TSTR];  // [k][m]
  __shared__ alignas(16) float WS[BKT*TSTR];  // [k][n]
  const int t = threadIdx.x;
  const int r0 = blockIdx.x * BMT;
  const int tx = t & 15, ty = t >> 4;
  float acc[8][8];
  #pragma unroll
  for (int i=0;i<8;i++)
    #pragma unroll
    for (int j=0;j<8;j++) acc[i][j] = 0.f;

  for (int kc0 = 0; kc0 < K; kc0 += BKT){
    for (int i = t; i < 1024; i += 256){
      int m = i >> 3, kk = (i & 7) << 2;
      float4 v = make_float4(0.f,0.f,0.f,0.f);
      if (r0 + m < M) v = *(const float4*)&A[(size_t)(r0+m)*K + kc0 + kk];
      AS[(kk+0)*TSTR + m] = v.x;
      AS[(kk+1)*TSTR + m] = v.y;
      AS[(kk+2)*TSTR + m] = v.z;
      AS[(kk+3)*TSTR + m] = v.w;
    }
    for (int i = t; i < 1024; i += 256){
      int k = i >> 5, nn = (i & 31) << 2;
      *(float4*)&WS[k*TSTR + nn] = *(const float4*)&W[(size_t)(kc0+k)*128 + nn];
    }
    __syncthreads();
    #pragma unroll 4
    for (int k = 0; k < BKT; k++){
      const float4 a0 = *(const float4*)&AS[k*TSTR + ty*8];
      const float4 a1 = *(const float4*)&AS[k*TSTR + ty*8 + 4];
      const float4 w0 = *(const float4*)&WS[k*TSTR + tx*8];
      const float4 w1 = *(const float4*)&WS[k*TSTR + tx*8 + 4];
      const float av[8] = {a0.x,a0.y,a0.z,a0.w,a1.x,a1.y,a1.z,a1.w};
      const float wv[8] = {w0.x,w0.y,w0.z,w0.w,w1.x,w1.y,w1.z,w1.w};
      #pragma unroll
      for (int i=0;i<8;i++)
        #pragma unroll
        for (int j=0;j<8;j++) acc[i][j] += av[i] * wv[j];
    }
    __syncthreads();
  }
  const float4 b0 = *(const float4*)&bias[tx*8];
  const float4 b1 = *(const float4*)&bias[tx*8+4];
  #pragma unroll
  for (int i=0;i<8;i++){
    int r = r0 + ty*8 + i;
    if (r < M){
      float4 o0 = make_float4(acc[i][0]+b0.x, acc[i][1]+b0.y, acc[i][2]+b0.z, acc[i][3]+b0.w);
      float4 o1 = make_float4(acc[i][4]+b1.x, acc[i][5]+b1.y, acc[i][6]+b1.z, acc[i][7]+b1.w);
      *(float4*)&C[(size_t)r*128 + tx*8]     = o0;
      *(float4*)&C[(size_t)r*128 + tx*8 + 4] = o1;
    }
  }
}

// ---------------- CSR build (once; topology shared by all 4 layers) ----------------
__global__ __launch_bounds__(256) void k_hist(const int* __restrict__ ei, int* __restrict__ counts){
  int e = blockIdx.x*256 + threadIdx.x;
  if (e < N_EDGES) atomicAdd(&counts[ei[N_EDGES + e]], 1);
}

__global__ __launch_bounds__(512) void k_scan1(const int* __restrict__ counts,
                                               int* __restrict__ incl,
                                               int* __restrict__ bsum){
  __shared__ int s[512];
  const int t = threadIdx.x;
  int i = blockIdx.x*512 + t;
  int v = (i < N_NODES) ? counts[i] : 0;
  s[t] = v;
  __syncthreads();
  for (int off = 1; off < 512; off <<= 1){
    int x = (t >= off) ? s[t - off] : 0;
    __syncthreads();
    s[t] += x;
    __syncthreads();
  }
  if (i < N_NODES) incl[i] = s[t];
  if (t == 511) bsum[blockIdx.x] = s[511];
}

__global__ __launch_bounds__(256) void k_scan2(int* __restrict__ bsum, int nb){
  __shared__ int s[256];
  const int t = threadIdx.x;
  int v = (t < nb) ? bsum[t] : 0;
  s[t] = v;
  __syncthreads();
  for (int off = 1; off < 256; off <<= 1){
    int x = (t >= off) ? s[t - off] : 0;
    __syncthreads();
    s[t] += x;
    __syncthreads();
  }
  if (t < nb) bsum[t] = s[t] - v;
}

__global__ __launch_bounds__(512) void k_scan3(const int* __restrict__ counts,
                                               const int* __restrict__ incl,
                                               const int* __restrict__ bsum,
                                               int* __restrict__ offsets,
                                               int* __restrict__ cursor){
  int i = blockIdx.x*512 + threadIdx.x;
  if (i >= N_NODES) return;
  int o = bsum[blockIdx.x] + incl[i];
  offsets[i + 1] = o;
  cursor[i]      = o - counts[i];
  if (i == 0) offsets[0] = 0;
}

__global__ __launch_bounds__(256) void k_scatter(const int* __restrict__ ei,
                                                 int* __restrict__ cursor,
                                                 int2* __restrict__ sedge){
  int e = blockIdx.x*256 + threadIdx.x;
  if (e >= N_EDGES) return;
  int dst = ei[N_EDGES + e];
  int pos = atomicAdd(&cursor[dst], 1);
  sedge[pos] = make_int2(ei[e], e);
}

// ---------------- Graph CSR from sorted batch (once) ----------------
__global__ __launch_bounds__(256) void k_ghist(const int* __restrict__ batch, int* __restrict__ gcnt){
  int i = blockIdx.x*256 + threadIdx.x;
  if (i < N_NODES) atomicAdd(&gcnt[batch[i]], 1);
}

__global__ __launch_bounds__(1024) void k_gscan(const int* __restrict__ gcnt, int* __restrict__ goff){
  __shared__ int s[1024];
  const int t = threadIdx.x;
  int v = gcnt[t];
  s[t] = v;
  __syncthreads();
  for (int off = 1; off < 1024; off <<= 1){
    int x = (t >= off) ? s[t - off] : 0;
    __syncthreads();
    s[t] += x;
    __syncthreads();
  }
  goff[t + 1] = s[t];
  if (t == 0) goff[0] = 0;
}

// ---------------- Fused GAT: per-dst-node softmax + aggregation, no atomics ----------------
__global__ __launch_bounds__(256) void k_gat(const float* __restrict__ xl,
                                             const float* __restrict__ xr,
                                             const float* __restrict__ ea,
                                             const float* __restrict__ We,
                                             const float* __restrict__ att,
                                             const int* __restrict__ offsets,
                                             const int2* __restrict__ sedge,
                                             float* __restrict__ aggr){
  __shared__ float WeS[16*128];
  __shared__ float attS[128];
  const int t = threadIdx.x;
  for (int i=t;i<16*128;i+=256) WeS[i] = We[i];
  if (t < 128) attS[t] = att[t];
  __syncthreads();
  const int wave = t >> 6, lane = t & 63;
  const int node = blockIdx.x*4 + wave;
  if (node >= N_NODES) return;
  const int c0 = lane*2;
  const int el = lane & 15;
  const float a0 = attS[c0], a1 = attS[c0+1];
  float2 wreg[16];                       // We columns c0,c0+1 in registers
  #pragma unroll
  for (int k=0;k<16;k++) wreg[k] = *(const float2*)&WeS[k*128 + c0];
  const float2 xrv = *(const float2*)(xr + (size_t)node*HID_ + c0);
  float acc0 = 0.f, acc1 = 0.f, den = 0.f;
  const int beg = offsets[node], end = offsets[node+1];
  int i = beg;
  for (; i + 1 < end; i += 2){
    int2 s0 = sedge[i], s1 = sedge[i+1];
    float2 vl0 = *(const float2*)(xl + (size_t)s0.x*HID_ + c0);
    float2 vl1 = *(const float2*)(xl + (size_t)s1.x*HID_ + c0);
    float av0 = ea[(size_t)s0.y*F_EDGE_ + el];   // coalesced, 1 load/lane
    float av1 = ea[(size_t)s1.y*F_EDGE_ + el];
    float e00=0.f, e01=0.f, e10=0.f, e11=0.f;
    #pragma unroll
    for (int k=0;k<16;k++){
      float b0 = __shfl(av0, k);
      float b1 = __shfl(av1, k);
      e00 += b0*wreg[k].x; e01 += b0*wreg[k].y;
      e10 += b1*wreg[k].x; e11 += b1*wreg[k].y;
    }
    float v00 = vl0.x + xrv.x + e00, v01 = vl0.y + xrv.y + e01;
    float v10 = vl1.x + xrv.x + e10, v11 = vl1.y + xrv.y + e11;
    v00 = v00 > 0.f ? v00 : 0.2f*v00;  v01 = v01 > 0.f ? v01 : 0.2f*v01;
    v10 = v10 > 0.f ? v10 : 0.2f*v10;  v11 = v11 > 0.f ? v11 : 0.2f*v11;
    float sc0 = v00*a0 + v01*a1;
    float sc1 = v10*a0 + v11*a1;
    sc0 += __shfl_xor(sc0, 1);  sc1 += __shfl_xor(sc1, 1);
    sc0 += __shfl_xor(sc0, 2);  sc1 += __shfl_xor(sc1, 2);
    sc0 += __shfl_xor(sc0, 4);  sc1 += __shfl_xor(sc1, 4);
    sc0 += __shfl_xor(sc0, 8);  sc1 += __shfl_xor(sc1, 8);
    float p0 = __expf(sc0), p1 = __expf(sc1);
    acc0 += p0*vl0.x + p1*vl1.x;
    acc1 += p0*vl0.y + p1*vl1.y;
    den  += p0 + p1;
  }
  if (i < end){
    int2 s0 = sedge[i];
    float2 vl0 = *(const float2*)(xl + (size_t)s0.x*HID_ + c0);
    float av0 = ea[(size_t)s0.y*F_EDGE_ + el];
    float e00=0.f, e01=0.f;
    #pragma unroll
    for (int k=0;k<16;k++){
      float b0 = __shfl(av0, k);
      e00 += b0*wreg[k].x; e01 += b0*wreg[k].y;
    }
    float v00 = vl0.x + xrv.x + e00, v01 = vl0.y + xrv.y + e01;
    v00 = v00 > 0.f ? v00 : 0.2f*v00;  v01 = v01 > 0.f ? v01 : 0.2f*v01;
    float sc0 = v00*a0 + v01*a1;
    sc0 += __shfl_xor(sc0, 1);
    sc0 += __shfl_xor(sc0, 2);
    sc0 += __shfl_xor(sc0, 4);
    sc0 += __shfl_xor(sc0, 8);
    float p0 = __expf(sc0);
    acc0 += p0*vl0.x;
    acc1 += p0*vl0.y;
    den  += p0;
  }
  float inv = 1.0f / (den + 1e-16f);
  *(float2*)(aggr + (size_t)node*HID_ + c0) = make_float2(acc0*inv, acc1*inv);
}

// ---------------- BN stats ----------------
__global__ __launch_bounds__(256) void k_bn_stats(const float* __restrict__ aggr,
                                                  float* __restrict__ stats){
  __shared__ float redS[256], redS2[256];
  const int t = threadIdx.x;
  const int c = t & 127, half = t >> 7;
  float s = 0.f, s2 = 0.f;
  for (int r = blockIdx.x*2 + half; r < N_NODES; r += gridDim.x*2){
    float v = aggr[(size_t)r*HID_ + c];
    s += v; s2 += v*v;
  }
  redS[t] = s; redS2[t] = s2;
  __syncthreads();
  if (half == 0){
    s  += redS[t+128];
    s2 += redS2[t+128];
    atomicAdd(&stats[c], s);
    atomicAdd(&stats[128+c], s2);
  }
}

// ---------------- BN apply + ELU (+ residual) ----------------
__global__ __launch_bounds__(256) void k_bn_apply(const float* __restrict__ aggr,
                                                  const float* __restrict__ stats,
                                                  const float* __restrict__ gamma,
                                                  const float* __restrict__ beta,
                                                  float* __restrict__ h, int residual){
  size_t i = (size_t)blockIdx.x*256 + threadIdx.x;
  if (i >= (size_t)N_NODES*HID_) return;
  int c = i & 127;
  const float invn = 1.0f / (float)N_NODES;
  float mu  = stats[c] * invn;
  float var = stats[128+c] * invn - mu*mu;
  float sc  = rsqrtf(var + 1e-5f) * gamma[c];
  float val = (aggr[i] - mu) * sc + beta[c];
  val = val > 0.f ? val : expm1f(val);
  if (residual) val += h[i];
  h[i] = val;
}

// ---------------- Pool: segmented mean over sorted batch, no atomics ----------------
__global__ __launch_bounds__(128) void k_pool_seg(const float* __restrict__ h,
                                                  const int* __restrict__ goff,
                                                  float* __restrict__ emb){
  const int g = blockIdx.x, c = threadIdx.x;
  const int beg = goff[g], end = goff[g+1];
  float acc = 0.f;
  for (int r = beg; r < end; r++) acc += h[(size_t)r*HID_ + c];
  float n = (float)(end - beg);
  emb[(size_t)g*HID_ + c] = acc / fmaxf(n, 1.f);
}

// ---------------- Per-task heads ----------------
__global__ __launch_bounds__(128) void k_heads(const float* __restrict__ emb,
                                               const float* __restrict__ mf,
                                               const int* __restrict__ fpi,
                                               const float* __restrict__ tw1,
                                               const float* __restrict__ tb1,
                                               const float* __restrict__ tw2,
                                               const float* __restrict__ tb2,
                                               float* __restrict__ out){
  const int g = blockIdx.x, task = blockIdx.y;
  const int j = threadIdx.x;
  __shared__ float fused[160];
  __shared__ float red[128];
  fused[j] = emb[(size_t)g*HID_ + j];
  if (j < 32){
    int bit = fpi[task*32 + j];
    fused[128 + j] = mf[(size_t)g*2048 + bit];
  }
  __syncthreads();
  const float* w1 = tw1 + (size_t)task*160*128;
  float acc = tb1[task*128 + j];
  #pragma unroll 8
  for (int i=0;i<160;i++) acc += fused[i] * w1[(size_t)i*128 + j];
  acc = acc > 0.f ? acc : 0.f;
  acc *= tw2[task*128 + j];
  red[j] = acc;
  __syncthreads();
  for (int s=64; s>0; s>>=1){
    if (j < s) red[j] += red[j+s];
    __syncthreads();
  }
  if (j == 0) out[(size_t)g*N_TASK + task] = red[0] + tb2[task];
}

extern "C" void kernel_launch(void* const* d_in, const int* in_sizes, int n_in,
                              void* d_out, int out_size, void* d_ws, size_t ws_size,
                              hipStream_t stream){
  const float* x    = (const float*)d_in[0];
  const int*   ei   = (const int*)  d_in[1];
  const float* ea   = (const float*)d_in[2];
  const int*   batch= (const int*)  d_in[3];
  const float* mf   = (const float*)d_in[4];
  const int*   fpi  = (const int*)  d_in[5];
  const float* Wl0  = (const float*)d_in[6];
  const float* bl0  = (const float*)d_in[7];
  const float* Wr0  = (const float*)d_in[8];
  const float* br0  = (const float*)d_in[9];
  const float* We0  = (const float*)d_in[10];
  const float* att0 = (const float*)d_in[11];
  const float* g0   = (const float*)d_in[13];
  const float* b0   = (const float*)d_in[14];
  const float* Wl   = (const float*)d_in[15];
  const float* bl   = (const float*)d_in[16];
  const float* Wr   = (const float*)d_in[17];
  const float* br   = (const float*)d_in[18];
  const float* We   = (const float*)d_in[19];
  const float* att  = (const float*)d_in[20];
  const float* gg   = (const float*)d_in[22];
  const float* bb   = (const float*)d_in[23];
  const float* tw1  = (const float*)d_in[24];
  const float* tb1  = (const float*)d_in[25];
  const float* tw2  = (const float*)d_in[26];
  const float* tb2  = (const float*)d_in[27];
  float* out = (float*)d_out;

  char* w = (char*)d_ws;
  auto alloc = [&](size_t bytes)->char*{ char* r = w; w += (bytes + 255) & ~(size_t)255; return r; };
  float* xl     = (float*)alloc((size_t)N_NODES*HID_*4);
  float* xr     = (float*)alloc((size_t)N_NODES*HID_*4);
  float* h      = (float*)alloc((size_t)N_NODES*HID_*4);
  float* aggr   = (float*)alloc((size_t)N_NODES*HID_*4);
  float* stats  = (float*)alloc(256*4);
  float* emb    = (float*)alloc((size_t)N_GRAPH*HID_*4);
  int*   counts = (int*)  alloc((size_t)N_NODES*4);
  int*   offsets= (int*)  alloc((size_t)(N_NODES+1)*4);
  int*   cursor = (int*)  alloc((size_t)N_NODES*4);
  int*   incl   = (int*)  alloc((size_t)N_NODES*4);
  int*   bsum   = (int*)  alloc(256*4);
  int2*  sedge  = (int2*) alloc((size_t)N_EDGES*8);
  int*   gcnt   = (int*)  alloc((size_t)N_GRAPH*4);
  int*   goff   = (int*)  alloc((size_t)(N_GRAPH+1)*4);

  const int gemm_grid = (N_NODES + BMT - 1)/BMT;
  const int eg256 = (N_EDGES + 255)/256;
  const int ng256 = (N_NODES + 255)/256;
  const int nscan = (N_NODES + 511)/512;

  // CSR build (topology constant across layers) + graph offsets
  hipMemsetAsync(counts, 0, (size_t)N_NODES*4, stream);
  hipMemsetAsync(gcnt,   0, (size_t)N_GRAPH*4, stream);
  hipLaunchKernelGGL(k_hist,    dim3(eg256), dim3(256), 0, stream, ei, counts);
  hipLaunchKernelGGL(k_ghist,   dim3(ng256), dim3(256), 0, stream, batch, gcnt);
  hipLaunchKernelGGL(k_scan1,   dim3(nscan), dim3(512), 0, stream, counts, incl, bsum);
  hipLaunchKernelGGL(k_scan2,   dim3(1),     dim3(256), 0, stream, bsum, nscan);
  hipLaunchKernelGGL(k_scan3,   dim3(nscan), dim3(512), 0, stream, counts, incl, bsum, offsets, cursor);
  hipLaunchKernelGGL(k_gscan,   dim3(1),     dim3(1024),0, stream, gcnt, goff);
  hipLaunchKernelGGL(k_scatter, dim3(eg256), dim3(256), 0, stream, ei, cursor, sedge);

  for (int layer = 0; layer < 4; layer++){
    const float *Wl_, *bl_, *Wr_, *br_, *We_, *att_, *g_, *b_, *Ain;
    int K;
    if (layer == 0){
      Wl_=Wl0; bl_=bl0; Wr_=Wr0; br_=br0; We_=We0; att_=att0; g_=g0; b_=b0;
      Ain = x; K = F_NODE_;
    } else {
      int i = layer - 1;
      Wl_ = Wl + (size_t)i*HID_*HID_;  bl_ = bl + (size_t)i*HID_;
      Wr_ = Wr + (size_t)i*HID_*HID_;  br_ = br + (size_t)i*HID_;
      We_ = We + (size_t)i*F_EDGE_*HID_;
      att_= att + (size_t)i*HID_;
      g_  = gg + (size_t)i*HID_;       b_  = bb + (size_t)i*HID_;
      Ain = h; K = HID_;
    }
    hipLaunchKernelGGL(k_gemm, dim3(gemm_grid), dim3(256), 0, stream, Ain, Wl_, bl_, xl, N_NODES, K);
    hipLaunchKernelGGL(k_gemm, dim3(gemm_grid), dim3(256), 0, stream, Ain, Wr_, br_, xr, N_NODES, K);
    hipMemsetAsync(stats, 0, 256*4, stream);
    hipLaunchKernelGGL(k_gat, dim3((N_NODES + 3)/4), dim3(256), 0, stream,
                       xl, xr, ea, We_, att_, offsets, sedge, aggr);
    hipLaunchKernelGGL(k_bn_stats, dim3(512), dim3(256), 0, stream, aggr, stats);
    hipLaunchKernelGGL(k_bn_apply, dim3((N_NODES*HID_ + 255)/256), dim3(256), 0, stream,
                       aggr, stats, g_, b_, h, layer > 0 ? 1 : 0);
  }
  hipLaunchKernelGGL(k_pool_seg, dim3(N_GRAPH), dim3(128), 0, stream, h, goff, emb);
  hipLaunchKernelGGL(k_heads, dim3(N_GRAPH, N_TASK), dim3(128), 0, stream, emb, mf, fpi, tw1, tb1, tw2, tb2, out);
}

// Round 6
// 1502.564 us; speedup vs baseline: 2.1094x; 1.0039x over previous
//
#include <hip/hip_runtime.h>
#include <hip/hip_bf16.h>

#define N_NODES 100000
#define N_EDGES 400000
#define F_NODE_ 64
#define F_EDGE_ 16
#define HID_ 128
#define N_GRAPH 1024
#define N_TASK 5

// ---------------- GEMM: C[M,128] = A[M,K] @ W[K,128] + bias, K in {64,128}, f32 ----------------
#define BMT 128
#define BKT 32
#define TSTR 132
__global__ __launch_bounds__(256) void k_gemm(const float* __restrict__ A,
                                              const float* __restrict__ W,
                                              const float* __restrict__ bias,
                                              float* __restrict__ C, int M, int K){
  __shared__ alignas(16) float AS[BKT*TSTR];  // [k][m]
  __shared__ alignas(16) float WS[BKT*TSTR];  // [k][n]
  const int t = threadIdx.x;
  const int r0 = blockIdx.x * BMT;
  const int tx = t & 15, ty = t >> 4;
  float acc[8][8];
  #pragma unroll
  for (int i=0;i<8;i++)
    #pragma unroll
    for (int j=0;j<8;j++) acc[i][j] = 0.f;

  for (int kc0 = 0; kc0 < K; kc0 += BKT){
    for (int i = t; i < 1024; i += 256){
      int m = i >> 3, kk = (i & 7) << 2;
      float4 v = make_float4(0.f,0.f,0.f,0.f);
      if (r0 + m < M) v = *(const float4*)&A[(size_t)(r0+m)*K + kc0 + kk];
      AS[(kk+0)*TSTR + m] = v.x;
      AS[(kk+1)*TSTR + m] = v.y;
      AS[(kk+2)*TSTR + m] = v.z;
      AS[(kk+3)*TSTR + m] = v.w;
    }
    for (int i = t; i < 1024; i += 256){
      int k = i >> 5, nn = (i & 31) << 2;
      *(float4*)&WS[k*TSTR + nn] = *(const float4*)&W[(size_t)(kc0+k)*128 + nn];
    }
    __syncthreads();
    #pragma unroll 4
    for (int k = 0; k < BKT; k++){
      const float4 a0 = *(const float4*)&AS[k*TSTR + ty*8];
      const float4 a1 = *(const float4*)&AS[k*TSTR + ty*8 + 4];
      const float4 w0 = *(const float4*)&WS[k*TSTR + tx*8];
      const float4 w1 = *(const float4*)&WS[k*TSTR + tx*8 + 4];
      const float av[8] = {a0.x,a0.y,a0.z,a0.w,a1.x,a1.y,a1.z,a1.w};
      const float wv[8] = {w0.x,w0.y,w0.z,w0.w,w1.x,w1.y,w1.z,w1.w};
      #pragma unroll
      for (int i=0;i<8;i++)
        #pragma unroll
        for (int j=0;j<8;j++) acc[i][j] += av[i] * wv[j];
    }
    __syncthreads();
  }
  const float4 b0 = *(const float4*)&bias[tx*8];
  const float4 b1 = *(const float4*)&bias[tx*8+4];
  #pragma unroll
  for (int i=0;i<8;i++){
    int r = r0 + ty*8 + i;
    if (r < M){
      float4 o0 = make_float4(acc[i][0]+b0.x, acc[i][1]+b0.y, acc[i][2]+b0.z, acc[i][3]+b0.w);
      float4 o1 = make_float4(acc[i][4]+b1.x, acc[i][5]+b1.y, acc[i][6]+b1.z, acc[i][7]+b1.w);
      *(float4*)&C[(size_t)r*128 + tx*8]     = o0;
      *(float4*)&C[(size_t)r*128 + tx*8 + 4] = o1;
    }
  }
}

// ---------------- CSR build (once; topology shared by all 4 layers) ----------------
__global__ __launch_bounds__(256) void k_hist(const int* __restrict__ ei, int* __restrict__ counts){
  int e = blockIdx.x*256 + threadIdx.x;
  if (e < N_EDGES) atomicAdd(&counts[ei[N_EDGES + e]], 1);
}

__global__ __launch_bounds__(512) void k_scan1(const int* __restrict__ counts,
                                               int* __restrict__ incl,
                                               int* __restrict__ bsum){
  __shared__ int s[512];
  const int t = threadIdx.x;
  int i = blockIdx.x*512 + t;
  int v = (i < N_NODES) ? counts[i] : 0;
  s[t] = v;
  __syncthreads();
  for (int off = 1; off < 512; off <<= 1){
    int x = (t >= off) ? s[t - off] : 0;
    __syncthreads();
    s[t] += x;
    __syncthreads();
  }
  if (i < N_NODES) incl[i] = s[t];
  if (t == 511) bsum[blockIdx.x] = s[511];
}

__global__ __launch_bounds__(256) void k_scan2(int* __restrict__ bsum, int nb){
  __shared__ int s[256];
  const int t = threadIdx.x;
  int v = (t < nb) ? bsum[t] : 0;
  s[t] = v;
  __syncthreads();
  for (int off = 1; off < 256; off <<= 1){
    int x = (t >= off) ? s[t - off] : 0;
    __syncthreads();
    s[t] += x;
    __syncthreads();
  }
  if (t < nb) bsum[t] = s[t] - v;
}

__global__ __launch_bounds__(512) void k_scan3(const int* __restrict__ counts,
                                               const int* __restrict__ incl,
                                               const int* __restrict__ bsum,
                                               int* __restrict__ offsets,
                                               int* __restrict__ cursor){
  int i = blockIdx.x*512 + threadIdx.x;
  if (i >= N_NODES) return;
  int o = bsum[blockIdx.x] + incl[i];
  offsets[i + 1] = o;
  cursor[i]      = o - counts[i];
  if (i == 0) offsets[0] = 0;
}

// scatter: edge record -> src only; edge features copied into CSR order
__global__ __launch_bounds__(256) void k_scatter(const int* __restrict__ ei,
                                                 int* __restrict__ cursor,
                                                 int* __restrict__ ssrc,
                                                 const float* __restrict__ ea,
                                                 float* __restrict__ ea_s){
  int e = blockIdx.x*256 + threadIdx.x;
  if (e >= N_EDGES) return;
  int dst = ei[N_EDGES + e];
  int pos = atomicAdd(&cursor[dst], 1);
  ssrc[pos] = ei[e];
  const float4* s4 = (const float4*)(ea + (size_t)e*F_EDGE_);
  float4* d4 = (float4*)(ea_s + (size_t)pos*F_EDGE_);
  d4[0] = s4[0]; d4[1] = s4[1]; d4[2] = s4[2]; d4[3] = s4[3];
}

// ---------------- Graph CSR from sorted batch (once) ----------------
__global__ __launch_bounds__(256) void k_ghist(const int* __restrict__ batch, int* __restrict__ gcnt){
  int i = blockIdx.x*256 + threadIdx.x;
  if (i < N_NODES) atomicAdd(&gcnt[batch[i]], 1);
}

__global__ __launch_bounds__(1024) void k_gscan(const int* __restrict__ gcnt, int* __restrict__ goff){
  __shared__ int s[1024];
  const int t = threadIdx.x;
  int v = gcnt[t];
  s[t] = v;
  __syncthreads();
  for (int off = 1; off < 1024; off <<= 1){
    int x = (t >= off) ? s[t - off] : 0;
    __syncthreads();
    s[t] += x;
    __syncthreads();
  }
  goff[t + 1] = s[t];
  if (t == 0) goff[0] = 0;
}

// ---------------- Fused GAT: per-dst-node softmax + aggregation, no atomics ----------------
// wave per node (grid-stride); lane covers 2 channels; ea pre-sorted to CSR order;
// batch-of-4 edge processing for memory-level parallelism.
#define GAT_GRID 3125
__global__ __launch_bounds__(256) void k_gat(const float* __restrict__ xl,
                                             const float* __restrict__ xr,
                                             const float* __restrict__ ea_s,
                                             const float* __restrict__ We,
                                             const float* __restrict__ att,
                                             const int* __restrict__ offsets,
                                             const int* __restrict__ ssrc,
                                             float* __restrict__ aggr){
  __shared__ float WeS[16*128];
  __shared__ float attS[128];
  const int t = threadIdx.x;
  for (int i=t;i<16*128;i+=256) WeS[i] = We[i];
  if (t < 128) attS[t] = att[t];
  __syncthreads();
  const int wave = t >> 6, lane = t & 63;
  const int c0 = lane*2;
  const int el = lane & 15;
  const float a0 = attS[c0], a1 = attS[c0+1];
  float2 wreg[16];
  #pragma unroll
  for (int k=0;k<16;k++) wreg[k] = *(const float2*)&WeS[k*128 + c0];

  for (int node = blockIdx.x*4 + wave; node < N_NODES; node += GAT_GRID*4){
    const float2 xrv = *(const float2*)(xr + (size_t)node*HID_ + c0);
    float acc0 = 0.f, acc1 = 0.f, den = 0.f;
    const int beg = offsets[node], end = offsets[node+1];
    for (int i = beg; i < end; i += 4){
      const int m = end - i;
      const int i1 = (m > 1) ? i+1 : i;
      const int i2 = (m > 2) ? i+2 : i;
      const int i3 = (m > 3) ? i+3 : i;
      // issue all independent loads first
      int s0 = ssrc[i], s1 = ssrc[i1], s2 = ssrc[i2], s3 = ssrc[i3];
      float av0 = ea_s[(size_t)i *F_EDGE_ + el];
      float av1 = ea_s[(size_t)i1*F_EDGE_ + el];
      float av2 = ea_s[(size_t)i2*F_EDGE_ + el];
      float av3 = ea_s[(size_t)i3*F_EDGE_ + el];
      float2 vl0 = *(const float2*)(xl + (size_t)s0*HID_ + c0);
      float2 vl1 = *(const float2*)(xl + (size_t)s1*HID_ + c0);
      float2 vl2 = *(const float2*)(xl + (size_t)s2*HID_ + c0);
      float2 vl3 = *(const float2*)(xl + (size_t)s3*HID_ + c0);
      float e00=0.f,e01=0.f,e10=0.f,e11=0.f,e20=0.f,e21=0.f,e30=0.f,e31=0.f;
      #pragma unroll
      for (int k=0;k<16;k++){
        float b0 = __shfl(av0, k);
        float b1 = __shfl(av1, k);
        float b2 = __shfl(av2, k);
        float b3 = __shfl(av3, k);
        e00 += b0*wreg[k].x; e01 += b0*wreg[k].y;
        e10 += b1*wreg[k].x; e11 += b1*wreg[k].y;
        e20 += b2*wreg[k].x; e21 += b2*wreg[k].y;
        e30 += b3*wreg[k].x; e31 += b3*wreg[k].y;
      }
      float v00 = vl0.x + xrv.x + e00, v01 = vl0.y + xrv.y + e01;
      float v10 = vl1.x + xrv.x + e10, v11 = vl1.y + xrv.y + e11;
      float v20 = vl2.x + xrv.x + e20, v21 = vl2.y + xrv.y + e21;
      float v30 = vl3.x + xrv.x + e30, v31 = vl3.y + xrv.y + e31;
      v00 = v00 > 0.f ? v00 : 0.2f*v00;  v01 = v01 > 0.f ? v01 : 0.2f*v01;
      v10 = v10 > 0.f ? v10 : 0.2f*v10;  v11 = v11 > 0.f ? v11 : 0.2f*v11;
      v20 = v20 > 0.f ? v20 : 0.2f*v20;  v21 = v21 > 0.f ? v21 : 0.2f*v21;
      v30 = v30 > 0.f ? v30 : 0.2f*v30;  v31 = v31 > 0.f ? v31 : 0.2f*v31;
      float sc0 = v00*a0 + v01*a1;
      float sc1 = v10*a0 + v11*a1;
      float sc2 = v20*a0 + v21*a1;
      float sc3 = v30*a0 + v31*a1;
      sc0 += __shfl_xor(sc0, 1); sc1 += __shfl_xor(sc1, 1); sc2 += __shfl_xor(sc2, 1); sc3 += __shfl_xor(sc3, 1);
      sc0 += __shfl_xor(sc0, 2); sc1 += __shfl_xor(sc1, 2); sc2 += __shfl_xor(sc2, 2); sc3 += __shfl_xor(sc3, 2);
      sc0 += __shfl_xor(sc0, 4); sc1 += __shfl_xor(sc1, 4); sc2 += __shfl_xor(sc2, 4); sc3 += __shfl_xor(sc3, 4);
      sc0 += __shfl_xor(sc0, 8); sc1 += __shfl_xor(sc1, 8); sc2 += __shfl_xor(sc2, 8); sc3 += __shfl_xor(sc3, 8);
      float p0 = __expf(sc0);
      float p1 = (m > 1) ? __expf(sc1) : 0.f;
      float p2 = (m > 2) ? __expf(sc2) : 0.f;
      float p3 = (m > 3) ? __expf(sc3) : 0.f;
      acc0 += p0*vl0.x + p1*vl1.x + p2*vl2.x + p3*vl3.x;
      acc1 += p0*vl0.y + p1*vl1.y + p2*vl2.y + p3*vl3.y;
      den  += p0 + p1 + p2 + p3;
    }
    float inv = 1.0f / (den + 1e-16f);
    *(float2*)(aggr + (size_t)node*HID_ + c0) = make_float2(acc0*inv, acc1*inv);
  }
}

// ---------------- BN stats ----------------
__global__ __launch_bounds__(256) void k_bn_stats(const float* __restrict__ aggr,
                                                  float* __restrict__ stats){
  __shared__ float redS[256], redS2[256];
  const int t = threadIdx.x;
  const int c = t & 127, half = t >> 7;
  float s = 0.f, s2 = 0.f;
  for (int r = blockIdx.x*2 + half; r < N_NODES; r += gridDim.x*2){
    float v = aggr[(size_t)r*HID_ + c];
    s += v; s2 += v*v;
  }
  redS[t] = s; redS2[t] = s2;
  __syncthreads();
  if (half == 0){
    s  += redS[t+128];
    s2 += redS2[t+128];
    atomicAdd(&stats[c], s);
    atomicAdd(&stats[128+c], s2);
  }
}

// ---------------- BN apply + ELU (+ residual) ----------------
__global__ __launch_bounds__(256) void k_bn_apply(const float* __restrict__ aggr,
                                                  const float* __restrict__ stats,
                                                  const float* __restrict__ gamma,
                                                  const float* __restrict__ beta,
                                                  float* __restrict__ h, int residual){
  size_t i = (size_t)blockIdx.x*256 + threadIdx.x;
  if (i >= (size_t)N_NODES*HID_) return;
  int c = i & 127;
  const float invn = 1.0f / (float)N_NODES;
  float mu  = stats[c] * invn;
  float var = stats[128+c] * invn - mu*mu;
  float sc  = rsqrtf(var + 1e-5f) * gamma[c];
  float val = (aggr[i] - mu) * sc + beta[c];
  val = val > 0.f ? val : expm1f(val);
  if (residual) val += h[i];
  h[i] = val;
}

// ---------------- Pool: segmented mean over sorted batch, no atomics ----------------
__global__ __launch_bounds__(128) void k_pool_seg(const float* __restrict__ h,
                                                  const int* __restrict__ goff,
                                                  float* __restrict__ emb){
  const int g = blockIdx.x, c = threadIdx.x;
  const int beg = goff[g], end = goff[g+1];
  float acc = 0.f;
  for (int r = beg; r < end; r++) acc += h[(size_t)r*HID_ + c];
  float n = (float)(end - beg);
  emb[(size_t)g*HID_ + c] = acc / fmaxf(n, 1.f);
}

// ---------------- Per-task heads ----------------
__global__ __launch_bounds__(128) void k_heads(const float* __restrict__ emb,
                                               const float* __restrict__ mf,
                                               const int* __restrict__ fpi,
                                               const float* __restrict__ tw1,
                                               const float* __restrict__ tb1,
                                               const float* __restrict__ tw2,
                                               const float* __restrict__ tb2,
                                               float* __restrict__ out){
  const int g = blockIdx.x, task = blockIdx.y;
  const int j = threadIdx.x;
  __shared__ float fused[160];
  __shared__ float red[128];
  fused[j] = emb[(size_t)g*HID_ + j];
  if (j < 32){
    int bit = fpi[task*32 + j];
    fused[128 + j] = mf[(size_t)g*2048 + bit];
  }
  __syncthreads();
  const float* w1 = tw1 + (size_t)task*160*128;
  float acc = tb1[task*128 + j];
  #pragma unroll 8
  for (int i=0;i<160;i++) acc += fused[i] * w1[(size_t)i*128 + j];
  acc = acc > 0.f ? acc : 0.f;
  acc *= tw2[task*128 + j];
  red[j] = acc;
  __syncthreads();
  for (int s=64; s>0; s>>=1){
    if (j < s) red[j] += red[j+s];
    __syncthreads();
  }
  if (j == 0) out[(size_t)g*N_TASK + task] = red[0] + tb2[task];
}

extern "C" void kernel_launch(void* const* d_in, const int* in_sizes, int n_in,
                              void* d_out, int out_size, void* d_ws, size_t ws_size,
                              hipStream_t stream){
  const float* x    = (const float*)d_in[0];
  const int*   ei   = (const int*)  d_in[1];
  const float* ea   = (const float*)d_in[2];
  const int*   batch= (const int*)  d_in[3];
  const float* mf   = (const float*)d_in[4];
  const int*   fpi  = (const int*)  d_in[5];
  const float* Wl0  = (const float*)d_in[6];
  const float* bl0  = (const float*)d_in[7];
  const float* Wr0  = (const float*)d_in[8];
  const float* br0  = (const float*)d_in[9];
  const float* We0  = (const float*)d_in[10];
  const float* att0 = (const float*)d_in[11];
  const float* g0   = (const float*)d_in[13];
  const float* b0   = (const float*)d_in[14];
  const float* Wl   = (const float*)d_in[15];
  const float* bl   = (const float*)d_in[16];
  const float* Wr   = (const float*)d_in[17];
  const float* br   = (const float*)d_in[18];
  const float* We   = (const float*)d_in[19];
  const float* att  = (const float*)d_in[20];
  const float* gg   = (const float*)d_in[22];
  const float* bb   = (const float*)d_in[23];
  const float* tw1  = (const float*)d_in[24];
  const float* tb1  = (const float*)d_in[25];
  const float* tw2  = (const float*)d_in[26];
  const float* tb2  = (const float*)d_in[27];
  float* out = (float*)d_out;

  char* w = (char*)d_ws;
  auto alloc = [&](size_t bytes)->char*{ char* r = w; w += (bytes + 255) & ~(size_t)255; return r; };
  float* xl     = (float*)alloc((size_t)N_NODES*HID_*4);
  float* xr     = (float*)alloc((size_t)N_NODES*HID_*4);
  float* h      = (float*)alloc((size_t)N_NODES*HID_*4);
  float* aggr   = (float*)alloc((size_t)N_NODES*HID_*4);
  float* stats  = (float*)alloc(256*4);
  float* emb    = (float*)alloc((size_t)N_GRAPH*HID_*4);
  int*   counts = (int*)  alloc((size_t)N_NODES*4);
  int*   offsets= (int*)  alloc((size_t)(N_NODES+1)*4);
  int*   cursor = (int*)  alloc((size_t)N_NODES*4);
  int*   incl   = (int*)  alloc((size_t)N_NODES*4);
  int*   bsum   = (int*)  alloc(256*4);
  int*   ssrc   = (int*)  alloc((size_t)N_EDGES*4);
  float* ea_s   = (float*)alloc((size_t)N_EDGES*F_EDGE_*4);
  int*   gcnt   = (int*)  alloc((size_t)N_GRAPH*4);
  int*   goff   = (int*)  alloc((size_t)(N_GRAPH+1)*4);

  const int gemm_grid = (N_NODES + BMT - 1)/BMT;
  const int eg256 = (N_EDGES + 255)/256;
  const int ng256 = (N_NODES + 255)/256;
  const int nscan = (N_NODES + 511)/512;

  // CSR build (topology constant across layers) + graph offsets
  hipMemsetAsync(counts, 0, (size_t)N_NODES*4, stream);
  hipMemsetAsync(gcnt,   0, (size_t)N_GRAPH*4, stream);
  hipLaunchKernelGGL(k_hist,    dim3(eg256), dim3(256), 0, stream, ei, counts);
  hipLaunchKernelGGL(k_ghist,   dim3(ng256), dim3(256), 0, stream, batch, gcnt);
  hipLaunchKernelGGL(k_scan1,   dim3(nscan), dim3(512), 0, stream, counts, incl, bsum);
  hipLaunchKernelGGL(k_scan2,   dim3(1),     dim3(256), 0, stream, bsum, nscan);
  hipLaunchKernelGGL(k_scan3,   dim3(nscan), dim3(512), 0, stream, counts, incl, bsum, offsets, cursor);
  hipLaunchKernelGGL(k_gscan,   dim3(1),     dim3(1024),0, stream, gcnt, goff);
  hipLaunchKernelGGL(k_scatter, dim3(eg256), dim3(256), 0, stream, ei, cursor, ssrc, ea, ea_s);

  for (int layer = 0; layer < 4; layer++){
    const float *Wl_, *bl_, *Wr_, *br_, *We_, *att_, *g_, *b_, *Ain;
    int K;
    if (layer == 0){
      Wl_=Wl0; bl_=bl0; Wr_=Wr0; br_=br0; We_=We0; att_=att0; g_=g0; b_=b0;
      Ain = x; K = F_NODE_;
    } else {
      int i = layer - 1;
      Wl_ = Wl + (size_t)i*HID_*HID_;  bl_ = bl + (size_t)i*HID_;
      Wr_ = Wr + (size_t)i*HID_*HID_;  br_ = br + (size_t)i*HID_;
      We_ = We + (size_t)i*F_EDGE_*HID_;
      att_= att + (size_t)i*HID_;
      g_  = gg + (size_t)i*HID_;       b_  = bb + (size_t)i*HID_;
      Ain = h; K = HID_;
    }
    hipLaunchKernelGGL(k_gemm, dim3(gemm_grid), dim3(256), 0, stream, Ain, Wl_, bl_, xl, N_NODES, K);
    hipLaunchKernelGGL(k_gemm, dim3(gemm_grid), dim3(256), 0, stream, Ain, Wr_, br_, xr, N_NODES, K);
    hipMemsetAsync(stats, 0, 256*4, stream);
    hipLaunchKernelGGL(k_gat, dim3(GAT_GRID), dim3(256), 0, stream,
                       xl, xr, ea_s, We_, att_, offsets, ssrc, aggr);
    hipLaunchKernelGGL(k_bn_stats, dim3(512), dim3(256), 0, stream, aggr, stats);
    hipLaunchKernelGGL(k_bn_apply, dim3((N_NODES*HID_ + 255)/256), dim3(256), 0, stream,
                       aggr, stats, g_, b_, h, layer > 0 ? 1 : 0);
  }
  hipLaunchKernelGGL(k_pool_seg, dim3(N_GRAPH), dim3(128), 0, stream, h, goff, emb);
  hipLaunchKernelGGL(k_heads, dim3(N_GRAPH, N_TASK), dim3(128), 0, stream, emb, mf, fpi, tw1, tb1, tw2, tb2, out);
}

// Round 7
// 1349.574 us; speedup vs baseline: 2.3486x; 1.1134x over previous
//
#include <hip/hip_runtime.h>
#include <hip/hip_bf16.h>

#define N_NODES 100000
#define N_EDGES 400000
#define F_NODE_ 64
#define F_EDGE_ 16
#define HID_ 128
#define N_GRAPH 1024
#define N_TASK 5

typedef unsigned short u16;
typedef __attribute__((ext_vector_type(8))) short frag8;   // 8 bf16 = 4 VGPRs
typedef __attribute__((ext_vector_type(4))) float f32x4;   // MFMA C/D

__device__ __forceinline__ float bu2f(u16 v){ return __uint_as_float(((unsigned)v) << 16); }
__device__ __forceinline__ float2 bp2f(unsigned u){
  return make_float2(__uint_as_float(u << 16), __uint_as_float(u & 0xFFFF0000u));
}
__device__ __forceinline__ u16 f2bu(float f){
  __hip_bfloat16 h = __float2bfloat16(f);
  return *(u16*)&h;
}

// ---------------- cast f32 -> bf16 ----------------
__global__ __launch_bounds__(256) void k_cast(const float* __restrict__ s, u16* __restrict__ d, int n){
  int i = blockIdx.x*256 + threadIdx.x;
  if (i < n) d[i] = f2bu(s[i]);
}

// ---------------- MFMA GEMM: C[M,128] = A[M,K] @ W[K,128] + bias; A,W,C bf16; K in {64,128} ----------------
// 256 thr = 4 waves; block covers 128 rows; wave w: rows r0+w*32 (2 row-tiles of 16).
// W staged in LDS pre-swizzled to B-fragment order (one ds_read_b128 per frag).
__global__ __launch_bounds__(256) void k_gemm_bf(const u16* __restrict__ A,
                                                 const u16* __restrict__ Wb,
                                                 const float* __restrict__ bias,
                                                 u16* __restrict__ C, int M, int K){
  __shared__ u16 WSf[4*8*64*8];   // up to K=128: (K/32)*8 tiles * 64 lanes * 8 elems
  const int t = threadIdx.x;
  for (int i = t; i < K*128; i += 256){
    int k = i >> 7, n = i & 127;
    int c = k >> 5, kk = k & 31;
    int l = ((kk >> 3) << 4) | (n & 15);
    WSf[(((c*8 + (n>>4))*64) + l)*8 + (kk & 7)] = Wb[i];
  }
  __syncthreads();
  const int l = t & 63, w = t >> 6;
  const int m = l & 15, quad = l >> 4;
  const int r0 = blockIdx.x * 128;
  const int rowA0 = r0 + w*32 + m;
  const int rowA1 = rowA0 + 16;
  f32x4 acc[2][8];
  #pragma unroll
  for (int i=0;i<2;i++)
    #pragma unroll
    for (int j=0;j<8;j++) acc[i][j] = (f32x4){0.f,0.f,0.f,0.f};
  const int KC = K >> 5;
  for (int c = 0; c < KC; c++){
    frag8 a0 = {}, a1 = {};
    if (rowA0 < M) a0 = *(const frag8*)(A + (size_t)rowA0*K + c*32 + quad*8);
    if (rowA1 < M) a1 = *(const frag8*)(A + (size_t)rowA1*K + c*32 + quad*8);
    #pragma unroll
    for (int n0 = 0; n0 < 8; n0++){
      frag8 b = *(const frag8*)&WSf[(((c*8 + n0)*64) + l)*8];
      acc[0][n0] = __builtin_amdgcn_mfma_f32_16x16x32_bf16(a0, b, acc[0][n0], 0,0,0);
      acc[1][n0] = __builtin_amdgcn_mfma_f32_16x16x32_bf16(a1, b, acc[1][n0], 0,0,0);
    }
  }
  #pragma unroll
  for (int rt = 0; rt < 2; rt++){
    int rbase = r0 + w*32 + rt*16 + quad*4;
    #pragma unroll
    for (int n0 = 0; n0 < 8; n0++){
      int col = n0*16 + m;
      float bc = bias[col];
      #pragma unroll
      for (int r = 0; r < 4; r++){
        int row = rbase + r;
        if (row < M) C[(size_t)row*128 + col] = f2bu(acc[rt][n0][r] + bc);
      }
    }
  }
}

// ---------------- CSR build (once; topology shared by all 4 layers) ----------------
__global__ __launch_bounds__(256) void k_hist(const int* __restrict__ ei, int* __restrict__ counts){
  int e = blockIdx.x*256 + threadIdx.x;
  if (e < N_EDGES) atomicAdd(&counts[ei[N_EDGES + e]], 1);
}

__global__ __launch_bounds__(512) void k_scan1(const int* __restrict__ counts,
                                               int* __restrict__ incl,
                                               int* __restrict__ bsum){
  __shared__ int s[512];
  const int t = threadIdx.x;
  int i = blockIdx.x*512 + t;
  int v = (i < N_NODES) ? counts[i] : 0;
  s[t] = v;
  __syncthreads();
  for (int off = 1; off < 512; off <<= 1){
    int x = (t >= off) ? s[t - off] : 0;
    __syncthreads();
    s[t] += x;
    __syncthreads();
  }
  if (i < N_NODES) incl[i] = s[t];
  if (t == 511) bsum[blockIdx.x] = s[511];
}

__global__ __launch_bounds__(256) void k_scan2(int* __restrict__ bsum, int nb){
  __shared__ int s[256];
  const int t = threadIdx.x;
  int v = (t < nb) ? bsum[t] : 0;
  s[t] = v;
  __syncthreads();
  for (int off = 1; off < 256; off <<= 1){
    int x = (t >= off) ? s[t - off] : 0;
    __syncthreads();
    s[t] += x;
    __syncthreads();
  }
  if (t < nb) bsum[t] = s[t] - v;
}

__global__ __launch_bounds__(512) void k_scan3(const int* __restrict__ counts,
                                               const int* __restrict__ incl,
                                               const int* __restrict__ bsum,
                                               int* __restrict__ offsets,
                                               int* __restrict__ cursor){
  int i = blockIdx.x*512 + threadIdx.x;
  if (i >= N_NODES) return;
  int o = bsum[blockIdx.x] + incl[i];
  offsets[i + 1] = o;
  cursor[i]      = o - counts[i];
  if (i == 0) offsets[0] = 0;
}

__global__ __launch_bounds__(256) void k_scatter(const int* __restrict__ ei,
                                                 int* __restrict__ cursor,
                                                 int* __restrict__ ssrc,
                                                 const float* __restrict__ ea,
                                                 float* __restrict__ ea_s){
  int e = blockIdx.x*256 + threadIdx.x;
  if (e >= N_EDGES) return;
  int dst = ei[N_EDGES + e];
  int pos = atomicAdd(&cursor[dst], 1);
  ssrc[pos] = ei[e];
  const float4* s4 = (const float4*)(ea + (size_t)e*F_EDGE_);
  float4* d4 = (float4*)(ea_s + (size_t)pos*F_EDGE_);
  d4[0] = s4[0]; d4[1] = s4[1]; d4[2] = s4[2]; d4[3] = s4[3];
}

// ---------------- Graph CSR from sorted batch (once) ----------------
__global__ __launch_bounds__(256) void k_ghist(const int* __restrict__ batch, int* __restrict__ gcnt){
  int i = blockIdx.x*256 + threadIdx.x;
  if (i < N_NODES) atomicAdd(&gcnt[batch[i]], 1);
}

__global__ __launch_bounds__(1024) void k_gscan(const int* __restrict__ gcnt, int* __restrict__ goff){
  __shared__ int s[1024];
  const int t = threadIdx.x;
  int v = gcnt[t];
  s[t] = v;
  __syncthreads();
  for (int off = 1; off < 1024; off <<= 1){
    int x = (t >= off) ? s[t - off] : 0;
    __syncthreads();
    s[t] += x;
    __syncthreads();
  }
  goff[t + 1] = s[t];
  if (t == 0) goff[0] = 0;
}

// ---------------- Fused GAT (bf16 xl/xr): per-dst-node softmax + aggregation ----------------
#define GAT_GRID 3125
__global__ __launch_bounds__(256) void k_gat(const u16* __restrict__ xl,
                                             const u16* __restrict__ xr,
                                             const float* __restrict__ ea_s,
                                             const float* __restrict__ We,
                                             const float* __restrict__ att,
                                             const int* __restrict__ offsets,
                                             const int* __restrict__ ssrc,
                                             float* __restrict__ aggr){
  __shared__ float WeS[16*128];
  __shared__ float attS[128];
  const int t = threadIdx.x;
  for (int i=t;i<16*128;i+=256) WeS[i] = We[i];
  if (t < 128) attS[t] = att[t];
  __syncthreads();
  const int wave = t >> 6, lane = t & 63;
  const int c0 = lane*2;
  const int el = lane & 15;
  const float a0 = attS[c0], a1 = attS[c0+1];
  float2 wreg[16];
  #pragma unroll
  for (int k=0;k<16;k++) wreg[k] = *(const float2*)&WeS[k*128 + c0];

  for (int node = blockIdx.x*4 + wave; node < N_NODES; node += GAT_GRID*4){
    const float2 xrv = bp2f(*(const unsigned*)(xr + (size_t)node*HID_ + c0));
    float acc0 = 0.f, acc1 = 0.f, den = 0.f;
    const int beg = offsets[node], end = offsets[node+1];
    for (int i = beg; i < end; i += 4){
      const int mm = end - i;
      const int i1 = (mm > 1) ? i+1 : i;
      const int i2 = (mm > 2) ? i+2 : i;
      const int i3 = (mm > 3) ? i+3 : i;
      int s0 = ssrc[i], s1 = ssrc[i1], s2 = ssrc[i2], s3 = ssrc[i3];
      float av0 = ea_s[(size_t)i *F_EDGE_ + el];
      float av1 = ea_s[(size_t)i1*F_EDGE_ + el];
      float av2 = ea_s[(size_t)i2*F_EDGE_ + el];
      float av3 = ea_s[(size_t)i3*F_EDGE_ + el];
      float2 vl0 = bp2f(*(const unsigned*)(xl + (size_t)s0*HID_ + c0));
      float2 vl1 = bp2f(*(const unsigned*)(xl + (size_t)s1*HID_ + c0));
      float2 vl2 = bp2f(*(const unsigned*)(xl + (size_t)s2*HID_ + c0));
      float2 vl3 = bp2f(*(const unsigned*)(xl + (size_t)s3*HID_ + c0));
      float e00=0.f,e01=0.f,e10=0.f,e11=0.f,e20=0.f,e21=0.f,e30=0.f,e31=0.f;
      #pragma unroll
      for (int k=0;k<16;k++){
        float b0 = __shfl(av0, k);
        float b1 = __shfl(av1, k);
        float b2 = __shfl(av2, k);
        float b3 = __shfl(av3, k);
        e00 += b0*wreg[k].x; e01 += b0*wreg[k].y;
        e10 += b1*wreg[k].x; e11 += b1*wreg[k].y;
        e20 += b2*wreg[k].x; e21 += b2*wreg[k].y;
        e30 += b3*wreg[k].x; e31 += b3*wreg[k].y;
      }
      float v00 = vl0.x + xrv.x + e00, v01 = vl0.y + xrv.y + e01;
      float v10 = vl1.x + xrv.x + e10, v11 = vl1.y + xrv.y + e11;
      float v20 = vl2.x + xrv.x + e20, v21 = vl2.y + xrv.y + e21;
      float v30 = vl3.x + xrv.x + e30, v31 = vl3.y + xrv.y + e31;
      v00 = v00 > 0.f ? v00 : 0.2f*v00;  v01 = v01 > 0.f ? v01 : 0.2f*v01;
      v10 = v10 > 0.f ? v10 : 0.2f*v10;  v11 = v11 > 0.f ? v11 : 0.2f*v11;
      v20 = v20 > 0.f ? v20 : 0.2f*v20;  v21 = v21 > 0.f ? v21 : 0.2f*v21;
      v30 = v30 > 0.f ? v30 : 0.2f*v30;  v31 = v31 > 0.f ? v31 : 0.2f*v31;
      float sc0 = v00*a0 + v01*a1;
      float sc1 = v10*a0 + v11*a1;
      float sc2 = v20*a0 + v21*a1;
      float sc3 = v30*a0 + v31*a1;
      sc0 += __shfl_xor(sc0, 1); sc1 += __shfl_xor(sc1, 1); sc2 += __shfl_xor(sc2, 1); sc3 += __shfl_xor(sc3, 1);
      sc0 += __shfl_xor(sc0, 2); sc1 += __shfl_xor(sc1, 2); sc2 += __shfl_xor(sc2, 2); sc3 += __shfl_xor(sc3, 2);
      sc0 += __shfl_xor(sc0, 4); sc1 += __shfl_xor(sc1, 4); sc2 += __shfl_xor(sc2, 4); sc3 += __shfl_xor(sc3, 4);
      sc0 += __shfl_xor(sc0, 8); sc1 += __shfl_xor(sc1, 8); sc2 += __shfl_xor(sc2, 8); sc3 += __shfl_xor(sc3, 8);
      float p0 = __expf(sc0);
      float p1 = (mm > 1) ? __expf(sc1) : 0.f;
      float p2 = (mm > 2) ? __expf(sc2) : 0.f;
      float p3 = (mm > 3) ? __expf(sc3) : 0.f;
      acc0 += p0*vl0.x + p1*vl1.x + p2*vl2.x + p3*vl3.x;
      acc1 += p0*vl0.y + p1*vl1.y + p2*vl2.y + p3*vl3.y;
      den  += p0 + p1 + p2 + p3;
    }
    float inv = 1.0f / (den + 1e-16f);
    *(float2*)(aggr + (size_t)node*HID_ + c0) = make_float2(acc0*inv, acc1*inv);
  }
}

// ---------------- BN stats ----------------
__global__ __launch_bounds__(256) void k_bn_stats(const float* __restrict__ aggr,
                                                  float* __restrict__ stats){
  __shared__ float redS[256], redS2[256];
  const int t = threadIdx.x;
  const int c = t & 127, half = t >> 7;
  float s = 0.f, s2 = 0.f;
  for (int r = blockIdx.x*2 + half; r < N_NODES; r += gridDim.x*2){
    float v = aggr[(size_t)r*HID_ + c];
    s += v; s2 += v*v;
  }
  redS[t] = s; redS2[t] = s2;
  __syncthreads();
  if (half == 0){
    s  += redS[t+128];
    s2 += redS2[t+128];
    atomicAdd(&stats[c], s);
    atomicAdd(&stats[128+c], s2);
  }
}

// ---------------- BN apply + ELU (+ residual), h in bf16 ----------------
__global__ __launch_bounds__(256) void k_bn_apply(const float* __restrict__ aggr,
                                                  const float* __restrict__ stats,
                                                  const float* __restrict__ gamma,
                                                  const float* __restrict__ beta,
                                                  u16* __restrict__ h, int residual){
  size_t i = (size_t)blockIdx.x*256 + threadIdx.x;
  if (i >= (size_t)N_NODES*HID_) return;
  int c = i & 127;
  const float invn = 1.0f / (float)N_NODES;
  float mu  = stats[c] * invn;
  float var = stats[128+c] * invn - mu*mu;
  float sc  = rsqrtf(var + 1e-5f) * gamma[c];
  float val = (aggr[i] - mu) * sc + beta[c];
  val = val > 0.f ? val : expm1f(val);
  if (residual) val += bu2f(h[i]);
  h[i] = f2bu(val);
}

// ---------------- Pool: segmented mean over sorted batch ----------------
__global__ __launch_bounds__(128) void k_pool_seg(const u16* __restrict__ h,
                                                  const int* __restrict__ goff,
                                                  float* __restrict__ emb){
  const int g = blockIdx.x, c = threadIdx.x;
  const int beg = goff[g], end = goff[g+1];
  float acc = 0.f;
  for (int r = beg; r < end; r++) acc += bu2f(h[(size_t)r*HID_ + c]);
  float n = (float)(end - beg);
  emb[(size_t)g*HID_ + c] = acc / fmaxf(n, 1.f);
}

// ---------------- Per-task heads ----------------
__global__ __launch_bounds__(128) void k_heads(const float* __restrict__ emb,
                                               const float* __restrict__ mf,
                                               const int* __restrict__ fpi,
                                               const float* __restrict__ tw1,
                                               const float* __restrict__ tb1,
                                               const float* __restrict__ tw2,
                                               const float* __restrict__ tb2,
                                               float* __restrict__ out){
  const int g = blockIdx.x, task = blockIdx.y;
  const int j = threadIdx.x;
  __shared__ float fused[160];
  __shared__ float red[128];
  fused[j] = emb[(size_t)g*HID_ + j];
  if (j < 32){
    int bit = fpi[task*32 + j];
    fused[128 + j] = mf[(size_t)g*2048 + bit];
  }
  __syncthreads();
  const float* w1 = tw1 + (size_t)task*160*128;
  float acc = tb1[task*128 + j];
  #pragma unroll 8
  for (int i=0;i<160;i++) acc += fused[i] * w1[(size_t)i*128 + j];
  acc = acc > 0.f ? acc : 0.f;
  acc *= tw2[task*128 + j];
  red[j] = acc;
  __syncthreads();
  for (int s=64; s>0; s>>=1){
    if (j < s) red[j] += red[j+s];
    __syncthreads();
  }
  if (j == 0) out[(size_t)g*N_TASK + task] = red[0] + tb2[task];
}

extern "C" void kernel_launch(void* const* d_in, const int* in_sizes, int n_in,
                              void* d_out, int out_size, void* d_ws, size_t ws_size,
                              hipStream_t stream){
  const float* x    = (const float*)d_in[0];
  const int*   ei   = (const int*)  d_in[1];
  const float* ea   = (const float*)d_in[2];
  const int*   batch= (const int*)  d_in[3];
  const float* mf   = (const float*)d_in[4];
  const int*   fpi  = (const int*)  d_in[5];
  const float* Wl0  = (const float*)d_in[6];
  const float* bl0  = (const float*)d_in[7];
  const float* Wr0  = (const float*)d_in[8];
  const float* br0  = (const float*)d_in[9];
  const float* We0  = (const float*)d_in[10];
  const float* att0 = (const float*)d_in[11];
  const float* g0   = (const float*)d_in[13];
  const float* b0   = (const float*)d_in[14];
  const float* Wl   = (const float*)d_in[15];
  const float* bl   = (const float*)d_in[16];
  const float* Wr   = (const float*)d_in[17];
  const float* br   = (const float*)d_in[18];
  const float* We   = (const float*)d_in[19];
  const float* att  = (const float*)d_in[20];
  const float* gg   = (const float*)d_in[22];
  const float* bb   = (const float*)d_in[23];
  const float* tw1  = (const float*)d_in[24];
  const float* tb1  = (const float*)d_in[25];
  const float* tw2  = (const float*)d_in[26];
  const float* tb2  = (const float*)d_in[27];
  float* out = (float*)d_out;

  char* w = (char*)d_ws;
  auto alloc = [&](size_t bytes)->char*{ char* r = w; w += (bytes + 255) & ~(size_t)255; return r; };
  u16*   xl     = (u16*)  alloc((size_t)N_NODES*HID_*2);
  u16*   xr     = (u16*)  alloc((size_t)N_NODES*HID_*2);
  u16*   h      = (u16*)  alloc((size_t)N_NODES*HID_*2);
  u16*   xbf    = (u16*)  alloc((size_t)N_NODES*F_NODE_*2);
  float* aggr   = (float*)alloc((size_t)N_NODES*HID_*4);
  float* stats  = (float*)alloc(256*4);
  float* emb    = (float*)alloc((size_t)N_GRAPH*HID_*4);
  int*   counts = (int*)  alloc((size_t)N_NODES*4);
  int*   offsets= (int*)  alloc((size_t)(N_NODES+1)*4);
  int*   cursor = (int*)  alloc((size_t)N_NODES*4);
  int*   incl   = (int*)  alloc((size_t)N_NODES*4);
  int*   bsum   = (int*)  alloc(256*4);
  int*   ssrc   = (int*)  alloc((size_t)N_EDGES*4);
  float* ea_s   = (float*)alloc((size_t)N_EDGES*F_EDGE_*4);
  int*   gcnt   = (int*)  alloc((size_t)N_GRAPH*4);
  int*   goff   = (int*)  alloc((size_t)(N_GRAPH+1)*4);
  u16*   Wl0b   = (u16*)  alloc((size_t)F_NODE_*HID_*2);
  u16*   Wr0b   = (u16*)  alloc((size_t)F_NODE_*HID_*2);
  u16*   Wlb    = (u16*)  alloc((size_t)3*HID_*HID_*2);
  u16*   Wrb    = (u16*)  alloc((size_t)3*HID_*HID_*2);

  const int eg256 = (N_EDGES + 255)/256;
  const int ng256 = (N_NODES + 255)/256;
  const int nscan = (N_NODES + 511)/512;
  const int gemm_grid = (N_NODES + 127)/128;

  // one-time: bf16 conversions
  hipLaunchKernelGGL(k_cast, dim3((N_NODES*F_NODE_ + 255)/256), dim3(256), 0, stream, x, xbf, N_NODES*F_NODE_);
  hipLaunchKernelGGL(k_cast, dim3((F_NODE_*HID_ + 255)/256),    dim3(256), 0, stream, Wl0, Wl0b, F_NODE_*HID_);
  hipLaunchKernelGGL(k_cast, dim3((F_NODE_*HID_ + 255)/256),    dim3(256), 0, stream, Wr0, Wr0b, F_NODE_*HID_);
  hipLaunchKernelGGL(k_cast, dim3((3*HID_*HID_ + 255)/256),     dim3(256), 0, stream, Wl,  Wlb,  3*HID_*HID_);
  hipLaunchKernelGGL(k_cast, dim3((3*HID_*HID_ + 255)/256),     dim3(256), 0, stream, Wr,  Wrb,  3*HID_*HID_);

  // CSR build (topology constant across layers) + graph offsets
  hipMemsetAsync(counts, 0, (size_t)N_NODES*4, stream);
  hipMemsetAsync(gcnt,   0, (size_t)N_GRAPH*4, stream);
  hipLaunchKernelGGL(k_hist,    dim3(eg256), dim3(256), 0, stream, ei, counts);
  hipLaunchKernelGGL(k_ghist,   dim3(ng256), dim3(256), 0, stream, batch, gcnt);
  hipLaunchKernelGGL(k_scan1,   dim3(nscan), dim3(512), 0, stream, counts, incl, bsum);
  hipLaunchKernelGGL(k_scan2,   dim3(1),     dim3(256), 0, stream, bsum, nscan);
  hipLaunchKernelGGL(k_scan3,   dim3(nscan), dim3(512), 0, stream, counts, incl, bsum, offsets, cursor);
  hipLaunchKernelGGL(k_gscan,   dim3(1),     dim3(1024),0, stream, gcnt, goff);
  hipLaunchKernelGGL(k_scatter, dim3(eg256), dim3(256), 0, stream, ei, cursor, ssrc, ea, ea_s);

  for (int layer = 0; layer < 4; layer++){
    const float *bl_, *br_, *We_, *att_, *g_, *b_;
    const u16 *Wlb_, *Wrb_, *Ain;
    int K;
    if (layer == 0){
      Wlb_=Wl0b; Wrb_=Wr0b; bl_=bl0; br_=br0; We_=We0; att_=att0; g_=g0; b_=b0;
      Ain = xbf; K = F_NODE_;
    } else {
      int i = layer - 1;
      Wlb_ = Wlb + (size_t)i*HID_*HID_;  bl_ = bl + (size_t)i*HID_;
      Wrb_ = Wrb + (size_t)i*HID_*HID_;  br_ = br + (size_t)i*HID_;
      We_ = We + (size_t)i*F_EDGE_*HID_;
      att_= att + (size_t)i*HID_;
      g_  = gg + (size_t)i*HID_;         b_  = bb + (size_t)i*HID_;
      Ain = h; K = HID_;
    }
    hipLaunchKernelGGL(k_gemm_bf, dim3(gemm_grid), dim3(256), 0, stream, Ain, Wlb_, bl_, xl, N_NODES, K);
    hipLaunchKernelGGL(k_gemm_bf, dim3(gemm_grid), dim3(256), 0, stream, Ain, Wrb_, br_, xr, N_NODES, K);
    hipMemsetAsync(stats, 0, 256*4, stream);
    hipLaunchKernelGGL(k_gat, dim3(GAT_GRID), dim3(256), 0, stream,
                       xl, xr, ea_s, We_, att_, offsets, ssrc, aggr);
    hipLaunchKernelGGL(k_bn_stats, dim3(512), dim3(256), 0, stream, aggr, stats);
    hipLaunchKernelGGL(k_bn_apply, dim3((N_NODES*HID_ + 255)/256), dim3(256), 0, stream,
                       aggr, stats, g_, b_, h, layer > 0 ? 1 : 0);
  }
  hipLaunchKernelGGL(k_pool_seg, dim3(N_GRAPH), dim3(128), 0, stream, h, goff, emb);
  hipLaunchKernelGGL(k_heads, dim3(N_GRAPH, N_TASK), dim3(128), 0, stream, emb, mf, fpi, tw1, tb1, tw2, tb2, out);
}